// Round 6
// baseline (154.704 us; speedup 1.0000x reference)
//
#include <hip/hip_runtime.h>
#include <hip/hip_bf16.h>

typedef __attribute__((ext_vector_type(8))) __bf16 bf16x8;
typedef __attribute__((ext_vector_type(4))) __bf16 bf16x4;
typedef __attribute__((ext_vector_type(4))) float  f32x4;

#define L2E 1.44269504088896340736f

static __device__ __forceinline__ f32x4 mfma16(bf16x8 a, bf16x8 b, f32x4 c) {
    return __builtin_amdgcn_mfma_f32_16x16x32_bf16(a, b, c, 0, 0, 0);
}

#define GLOAD_LDS16(gsrc, ldst)                                                \
    __builtin_amdgcn_global_load_lds(                                          \
        (const __attribute__((address_space(1))) unsigned int*)(gsrc),         \
        (__attribute__((address_space(3))) unsigned int*)(ldst), 16, 0, 0)

// ---------------- Weight prep: th_w, ph_w, g_w [128x256], W_w [256x128] -> bf16 -------------
__global__ __launch_bounds__(256) void prep_w(
    const float* __restrict__ thw, const float* __restrict__ phw,
    const float* __restrict__ gw,  const float* __restrict__ Ww,
    __bf16* __restrict__ wbf)
{
    const int idx  = blockIdx.x * 256 + threadIdx.x;
    const int base = idx * 4;
    const float* src = (base < 32768) ? thw : (base < 65536) ? phw
                     : (base < 98304) ? gw  : Ww;
    const int off = base & 32767;
    f32x4 v = *reinterpret_cast<const f32x4*>(src + off);
    bf16x4 o;
    #pragma unroll
    for (int i = 0; i < 4; ++i) o[i] = (__bf16)v[i];
    *reinterpret_cast<bf16x4*>(wbf + base) = o;
}

// ---------------- x [B,C,N] f32 -> xT [B,N,256] bf16 ----------------------------------------
__global__ __launch_bounds__(256) void xT_kernel(
    const float* __restrict__ x, __bf16* __restrict__ xT)
{
    __shared__ float tile[64][65];
    const int b  = blockIdx.z;
    const int c0 = blockIdx.y * 64;
    const int n0 = blockIdx.x * 64;
    const int tr = threadIdx.x >> 4;
    const int tc = threadIdx.x & 15;
    #pragma unroll
    for (int k = 0; k < 4; ++k) {
        int c = k * 16 + tr;
        f32x4 v = *reinterpret_cast<const f32x4*>(
            x + ((size_t)b * 256 + c0 + c) * 4096 + n0 + tc * 4);
        #pragma unroll
        for (int i = 0; i < 4; ++i) tile[c][tc * 4 + i] = v[i];
    }
    __syncthreads();
    #pragma unroll
    for (int k = 0; k < 4; ++k) {
        int n = k * 16 + tr;
        bf16x4 v;
        #pragma unroll
        for (int i = 0; i < 4; ++i) v[i] = (__bf16)tile[tc * 4 + i][n];
        *reinterpret_cast<bf16x4*>(xT + ((size_t)b * 4096 + n0 + n) * 256 + c0 + tc * 4) = v;
    }
}

// ---------------- proj MFMA: out[b,n,o] = sum_c xT[b,n,c] w[o,c] + bias[o], bf16 ------------
__global__ __launch_bounds__(256, 1) void proj_mfma(
    const __bf16* __restrict__ xT, const __bf16* __restrict__ wbf,
    const float* __restrict__ bth, const float* __restrict__ bph,
    const float* __restrict__ bg,
    __bf16* __restrict__ thetaT, __bf16* __restrict__ phiT, __bf16* __restrict__ gT)
{
    const int p    = blockIdx.y;
    const int b    = blockIdx.z;
    const int n0   = blockIdx.x * 64;
    const int w    = threadIdx.x >> 6;
    const int lane = threadIdx.x & 63;
    const int lo   = lane & 15;
    const int hi   = lane >> 4;

    __shared__ alignas(16) __bf16 XA[64 * 256];
    __shared__ alignas(16) __bf16 WL[128 * 256];

    const __bf16* wsrc  = wbf + p * 32768;
    const float*  bias  = (p == 0) ? bth : (p == 1) ? bph : bg;
    __bf16*       out   = (p == 0) ? thetaT : (p == 1) ? phiT : gT;
    const __bf16* xbase = xT + ((size_t)b * 4096 + n0) * 256;

    #pragma unroll
    for (int u = 0; u < 8; ++u) {
        const int chunk = (w * 8 + u) * 64 + lane;
        const int row   = chunk >> 5;
        const int jb    = (chunk & 31) * 16;
        const int sb    = row * 512 + (jb ^ ((row & 7) << 4));
        GLOAD_LDS16(xbase + (sb >> 1), &XA[(w * 8 + u) * 512]);
    }
    #pragma unroll
    for (int u = 0; u < 16; ++u) {
        const int chunk = (w * 16 + u) * 64 + lane;
        const int row   = chunk >> 5;
        const int jb    = (chunk & 31) * 16;
        const int sb    = row * 512 + (jb ^ ((row & 7) << 4));
        GLOAD_LDS16(wsrc + (sb >> 1), &WL[(w * 16 + u) * 512]);
    }
    __syncthreads();

    f32x4 C[8];
    #pragma unroll
    for (int cc = 0; cc < 8; ++cc) C[cc] = f32x4{0.f, 0.f, 0.f, 0.f};

    const int arow = w * 16 + lo;
    #pragma unroll
    for (int kb = 0; kb < 8; ++kb) {
        const int koff = kb * 64 + hi * 16;
        bf16x8 a = *reinterpret_cast<const bf16x8*>(
            (const char*)XA + arow * 512 + (koff ^ ((arow & 7) << 4)));
        bf16x8 bb[8];
        #pragma unroll
        for (int cc = 0; cc < 8; ++cc) {
            const int o = cc * 16 + lo;
            bb[cc] = *reinterpret_cast<const bf16x8*>(
                (const char*)WL + o * 512 + (koff ^ ((o & 7) << 4)));
        }
        #pragma unroll
        for (int cc = 0; cc < 8; ++cc) C[cc] = mfma16(a, bb[cc], C[cc]);
    }

    const int nbase = n0 + w * 16;
    #pragma unroll
    for (int cc = 0; cc < 8; ++cc) {
        const float bv = bias[cc * 16 + lo];
        #pragma unroll
        for (int r = 0; r < 4; ++r)
            out[((size_t)b * 4096 + nbase + 4 * hi + r) * 128 + cc * 16 + lo] =
                (__bf16)(C[cc][r] + bv);
    }
}

// ---------------- Transpose gT [B,N,128] -> blocked gBlk[b][mt][c][32] (bf16) ---------------
__global__ __launch_bounds__(256) void transpose_g(
    const __bf16* __restrict__ gT, __bf16* __restrict__ gBlk)
{
    __shared__ __bf16 tile[64][66];
    const int b  = blockIdx.z;
    const int c0 = blockIdx.y * 64;
    const int n0 = blockIdx.x * 64;
    const int tr = threadIdx.x >> 4;
    const int tc = threadIdx.x & 15;
    #pragma unroll
    for (int k = 0; k < 4; ++k) {
        int row = k * 16 + tr;
        bf16x4 v = *reinterpret_cast<const bf16x4*>(
            gT + ((size_t)b * 4096 + n0 + row) * 128 + c0 + tc * 4);
        #pragma unroll
        for (int i = 0; i < 4; ++i) tile[row][tc * 4 + i] = v[i];
    }
    __syncthreads();
    #pragma unroll
    for (int k = 0; k < 4; ++k) {
        int c = k * 16 + tr;
        int n = n0 + tc * 4;
        int mt = n >> 5, mm = n & 31;
        bf16x4 v;
        #pragma unroll
        for (int i = 0; i < 4; ++i) v[i] = tile[tc * 4 + i][c];
        *reinterpret_cast<bf16x4*>(
            gBlk + (((size_t)(b * 128 + mt) * 128) + (c0 + c)) * 32 + mm) = v;
    }
}

// ---------------- Flash attention (no-max softmax), LDS-staged KV, KV-split xNCH ------------
// 4 waves/block, 32 q/wave. plds: one 16-row buffer/wave, time-shared across the two
// q-halves (explicit lgkmcnt(0) between halves). P rows granule-XOR'd: byte ^= (hi<<4).
template<int NCH>
__global__ __launch_bounds__(256, 4) void attn_kernel(
    const __bf16* __restrict__ thetaT, const __bf16* __restrict__ phiT,
    const __bf16* __restrict__ gBlk, __bf16* __restrict__ yPart,
    float* __restrict__ lPart)
{
    constexpr int SH = (NCH == 8) ? 3 : 2;
    constexpr int NT = (4096 / NCH) / 32;
    const int bid   = blockIdx.x;
    const int chunk = bid & (NCH - 1);
    const int qb    = (bid >> SH) & 31;
    const int b     = bid >> (SH + 5);
    const int w     = threadIdx.x >> 6;
    const int lane  = threadIdx.x & 63;
    const int lo    = lane & 15;
    const int hi    = lane >> 4;
    const int Q0    = qb * 128 + w * 32;
    const int kvbase = chunk * (4096 / NCH);

    __shared__ alignas(16) __bf16 Kt[2][32 * 128];
    __shared__ alignas(16) __bf16 Vt[2][128 * 32];
    __shared__ alignas(16) __bf16 plds[4][16 * 40];   // 16-row P buffer per wave, 80B rows

    bf16x8 qf[2][4];
    #pragma unroll
    for (int qq = 0; qq < 2; ++qq) {
        const size_t qrow = ((size_t)b * 4096 + Q0 + qq * 16 + lo) * 128 + hi * 8;
        #pragma unroll
        for (int kb = 0; kb < 4; ++kb)
            qf[qq][kb] = *reinterpret_cast<const bf16x8*>(thetaT + qrow + kb * 32);
    }

    f32x4 yacc[2][8], yl[2];
    #pragma unroll
    for (int qq = 0; qq < 2; ++qq) {
        yl[qq] = f32x4{0.f, 0.f, 0.f, 0.f};
        #pragma unroll
        for (int cc = 0; cc < 8; ++cc) yacc[qq][cc] = f32x4{0.f, 0.f, 0.f, 0.f};
    }
    bf16x8 onesf;
    #pragma unroll
    for (int e = 0; e < 8; ++e) onesf[e] = (__bf16)1.0f;

    const __bf16* phiB   = phiT + (size_t)b * 4096 * 128;
    const __bf16* gBlk_b = gBlk + (size_t)b * 128 * 4096;
    char* pw = (char*)&plds[w][0];

    auto stage = [&](int buf, int t) {
        const int kv = kvbase + t * 32;
        #pragma unroll
        for (int u = 0; u < 2; ++u) {
            const int ii   = w + u * 4;
            const int mrow = ii * 4 + (lane >> 4);
            const int cbl  = ((lane & 15) * 16) ^ ((mrow & 7) << 4);
            const __bf16* src = phiB + ((size_t)(kv + mrow) << 7) + (cbl >> 1);
            GLOAD_LDS16(src, &Kt[buf][ii * 512]);
        }
        const __bf16* vtile = gBlk_b + ((size_t)(kv >> 5) << 12);
        #pragma unroll
        for (int u = 0; u < 2; ++u) {
            const int jj = w + u * 4;
            const int ch = jj * 64 + lane;
            const int c  = ch >> 2;
            const int h  = (ch & 3) ^ (c & 3);
            const __bf16* src = vtile + c * 32 + h * 8;
            GLOAD_LDS16(src, &Vt[buf][jj * 512]);
        }
    };

    stage(0, 0);

    #pragma unroll 1
    for (int t = 0; t < NT; ++t) {
        const int cur = t & 1;
        if (t < NT - 1) {
            stage(cur ^ 1, t + 1);
            asm volatile("s_waitcnt vmcnt(4)" ::: "memory");
        } else {
            asm volatile("s_waitcnt vmcnt(0)" ::: "memory");
        }
        __builtin_amdgcn_s_barrier();
        __builtin_amdgcn_sched_barrier(0);

        const __bf16* Kb = &Kt[cur][0];
        const __bf16* Vb = &Vt[cur][0];

        f32x4 f0[2], f1[2];
        f0[0] = f0[1] = f1[0] = f1[1] = f32x4{0.f, 0.f, 0.f, 0.f};
        #pragma unroll
        for (int kb = 0; kb < 4; ++kb) {
            const int cb = (kb * 64 + hi * 16) ^ ((lo & 7) << 4);
            bf16x8 b0 = *reinterpret_cast<const bf16x8*>(Kb + lo * 128 + (cb >> 1));
            bf16x8 b1 = *reinterpret_cast<const bf16x8*>(Kb + (16 + lo) * 128 + (cb >> 1));
            #pragma unroll
            for (int qq = 0; qq < 2; ++qq) {
                f0[qq] = mfma16(qf[qq][kb], b0, f0[qq]);
                f1[qq] = mfma16(qf[qq][kb], b1, f1[qq]);
            }
        }

        // P -> LDS (granule-XOR'd rows) -> A-fragments; one 16-row buffer per wave,
        // written for qq=0, read, then overwritten for qq=1 (lgkmcnt(0) guards WAR).
        bf16x8 pa0, pa1;
        {
            #pragma unroll
            for (int r = 0; r < 4; ++r) {
                float p0 = __builtin_amdgcn_exp2f(f0[0][r] * L2E);
                float p1 = __builtin_amdgcn_exp2f(f1[0][r] * L2E);
                char* bp = pw + (4 * hi + r) * 80;
                *(__bf16*)(bp + ((2 * lo) ^ (hi << 4)))      = (__bf16)p0;
                *(__bf16*)(bp + ((32 + 2 * lo) ^ (hi << 4))) = (__bf16)p1;
            }
            pa0 = *reinterpret_cast<const bf16x8*>(
                pw + lo * 80 + ((hi << 4) ^ ((lo & 12) << 2)));
            asm volatile("s_waitcnt lgkmcnt(0)" ::: "memory");
            __builtin_amdgcn_sched_barrier(0);
            #pragma unroll
            for (int r = 0; r < 4; ++r) {
                float p0 = __builtin_amdgcn_exp2f(f0[1][r] * L2E);
                float p1 = __builtin_amdgcn_exp2f(f1[1][r] * L2E);
                char* bp = pw + (4 * hi + r) * 80;
                *(__bf16*)(bp + ((2 * lo) ^ (hi << 4)))      = (__bf16)p0;
                *(__bf16*)(bp + ((32 + 2 * lo) ^ (hi << 4))) = (__bf16)p1;
            }
            pa1 = *reinterpret_cast<const bf16x8*>(
                pw + lo * 80 + ((hi << 4) ^ ((lo & 12) << 2)));
        }

        yl[0] = mfma16(pa0, onesf, yl[0]);
        yl[1] = mfma16(pa1, onesf, yl[1]);
        #pragma unroll
        for (int cc = 0; cc < 8; ++cc) {
            const int vr = cc * 16 + lo;
            bf16x8 gb = *reinterpret_cast<const bf16x8*>(
                Vb + vr * 32 + ((hi ^ (vr & 3)) * 8));
            yacc[0][cc] = mfma16(pa0, gb, yacc[0][cc]);
            yacc[1][cc] = mfma16(pa1, gb, yacc[1][cc]);
        }

        asm volatile("" ::: "memory");
        __builtin_amdgcn_s_barrier();
        __builtin_amdgcn_sched_barrier(0);
    }

    const int bc = chunk * 4 + b;
    #pragma unroll
    for (int qq = 0; qq < 2; ++qq)
        #pragma unroll
        for (int r = 0; r < 4; ++r) {
            const int row = Q0 + qq * 16 + 4 * hi + r;
            const size_t base = ((size_t)bc * 4096 + row) * 128;
            #pragma unroll
            for (int cc = 0; cc < 8; ++cc)
                yPart[base + cc * 16 + lo] = (__bf16)yacc[qq][cc][r];
            if (lo == 0)
                lPart[(size_t)bc * 4096 + row] = yl[qq][r];
        }
}

// ---------------- Merge the NC KV-chunk partials: yT = sum(y_c)/sum(l_c), bf16 --------------
template<int NC>
__global__ __launch_bounds__(256) void merge_kernel(
    const __bf16* __restrict__ yPart, const float* __restrict__ lPart,
    __bf16* __restrict__ yT)
{
    const int idx = blockIdx.x * 256 + threadIdx.x;  // 524288 total
    const int row = idx >> 5;
    const int c4  = (idx & 31) * 4;
    float lsum = 0.f;
    #pragma unroll
    for (int c = 0; c < NC; ++c) lsum += lPart[(size_t)c * 16384 + row];
    const float inv = 1.0f / lsum;
    float s[4] = {0.f, 0.f, 0.f, 0.f};
    #pragma unroll
    for (int c = 0; c < NC; ++c) {
        bf16x4 v = *reinterpret_cast<const bf16x4*>(
            yPart + (size_t)c * 2097152 + (size_t)row * 128 + c4);
        #pragma unroll
        for (int i = 0; i < 4; ++i) s[i] += (float)v[i];
    }
    bf16x4 o;
    #pragma unroll
    for (int i = 0; i < 4; ++i) o[i] = (__bf16)(s[i] * inv);
    *reinterpret_cast<bf16x4*>(yT + (size_t)row * 128 + c4) = o;
}

// ---------------- wy MFMA: Wy[b,o,n] = sum_ci Wbf[o,ci] yT[b,n,ci] + Wb[o], f32 -------------
__global__ __launch_bounds__(256, 1) void wy_mfma(
    const __bf16* __restrict__ yT, const __bf16* __restrict__ wW,
    const float* __restrict__ Wb, float* __restrict__ Wy)
{
    const int b    = blockIdx.y;
    const int n0   = blockIdx.x * 128;
    const int w    = threadIdx.x >> 6;
    const int lane = threadIdx.x & 63;
    const int lo   = lane & 15;
    const int hi   = lane >> 4;

    __shared__ alignas(16) __bf16 YL[128 * 128];
    __shared__ alignas(16) __bf16 WL[256 * 128];

    const __bf16* ybase = yT + ((size_t)b * 4096 + n0) * 128;
    #pragma unroll
    for (int u = 0; u < 8; ++u) {
        const int chunk = (w * 8 + u) * 64 + lane;
        const int row   = chunk >> 4;
        const int jb    = (chunk & 15) * 16;
        const int sb    = row * 256 + (jb ^ ((row & 7) << 4));
        GLOAD_LDS16(ybase + (sb >> 1), &YL[(w * 8 + u) * 512]);
    }
    #pragma unroll
    for (int u = 0; u < 16; ++u) {
        const int chunk = (w * 16 + u) * 64 + lane;
        const int row   = chunk >> 4;
        const int jb    = (chunk & 15) * 16;
        const int sb    = row * 256 + (jb ^ ((row & 7) << 4));
        GLOAD_LDS16(wW + (sb >> 1), &WL[(w * 16 + u) * 512]);
    }
    __syncthreads();

    f32x4 C[4][8];
    #pragma unroll
    for (int og = 0; og < 4; ++og)
        #pragma unroll
        for (int ct = 0; ct < 8; ++ct) C[og][ct] = f32x4{0.f, 0.f, 0.f, 0.f};

    #pragma unroll
    for (int kb = 0; kb < 4; ++kb) {
        const int koff = kb * 64 + hi * 16;
        bf16x8 a[4], bb[8];
        #pragma unroll
        for (int og = 0; og < 4; ++og) {
            const int o = w * 64 + og * 16 + lo;
            a[og] = *reinterpret_cast<const bf16x8*>(
                (const char*)WL + o * 256 + (koff ^ ((o & 7) << 4)));
        }
        #pragma unroll
        for (int ct = 0; ct < 8; ++ct) {
            const int nl = ct * 16 + lo;
            bb[ct] = *reinterpret_cast<const bf16x8*>(
                (const char*)YL + nl * 256 + (koff ^ ((nl & 7) << 4)));
        }
        #pragma unroll
        for (int og = 0; og < 4; ++og)
            #pragma unroll
            for (int ct = 0; ct < 8; ++ct)
                C[og][ct] = mfma16(a[og], bb[ct], C[og][ct]);
    }

    #pragma unroll
    for (int og = 0; og < 4; ++og)
        #pragma unroll
        for (int r = 0; r < 4; ++r) {
            const int o  = w * 64 + og * 16 + 4 * hi + r;
            const float bv = Wb[o];
            #pragma unroll
            for (int ct = 0; ct < 8; ++ct)
                Wy[((size_t)b * 256 + o) * 4096 + n0 + ct * 16 + lo] = C[og][ct][r] + bv;
        }
}

// ---------------- Per-channel BN stats over (B, N) ------------------------------------------
__global__ __launch_bounds__(256) void stats_kernel(
    const float* __restrict__ Wy, const float* __restrict__ gamma,
    const float* __restrict__ beta, float* __restrict__ stats)
{
    const int o = blockIdx.x;
    float s = 0.f, q = 0.f;
    for (int i = threadIdx.x; i < 16384; i += 256) {
        int b = i >> 12, n = i & 4095;
        float v = Wy[((size_t)b * 256 + o) * 4096 + n];
        s += v; q += v * v;
    }
    #pragma unroll
    for (int off = 32; off >= 1; off >>= 1) {
        s += __shfl_down(s, off);
        q += __shfl_down(q, off);
    }
    __shared__ float red[8];
    const int wid = threadIdx.x >> 6;
    if ((threadIdx.x & 63) == 0) { red[wid] = s; red[4 + wid] = q; }
    __syncthreads();
    if (threadIdx.x == 0) {
        float S = red[0] + red[1] + red[2] + red[3];
        float Q = red[4] + red[5] + red[6] + red[7];
        float mean = S * (1.f / 16384.f);
        float var  = Q * (1.f / 16384.f) - mean * mean;
        float scl  = gamma[o] * rsqrtf(var + 1e-5f);
        stats[o]       = scl;
        stats[256 + o] = beta[o] - mean * scl;
    }
}

// ---------------- out = Wy*scale + shift + x ------------------------------------------------
__global__ __launch_bounds__(256) void final_kernel(
    const float* __restrict__ Wy, const float* __restrict__ x,
    const float* __restrict__ stats, float* __restrict__ out)
{
    const int idx = blockIdx.x * 256 + threadIdx.x;
    const int o   = (idx >> 10) & 255;
    f32x4 wy = *reinterpret_cast<const f32x4*>(Wy + (size_t)idx * 4);
    f32x4 xv = *reinterpret_cast<const f32x4*>(x  + (size_t)idx * 4);
    f32x4 res = wy * stats[o] + stats[256 + o] + xv;
    *reinterpret_cast<f32x4*>(out + (size_t)idx * 4) = res;
}

extern "C" void kernel_launch(void* const* d_in, const int* in_sizes, int n_in,
                              void* d_out, int out_size, void* d_ws, size_t ws_size,
                              hipStream_t stream)
{
    const float* x    = (const float*)d_in[0];
    const float* g_w  = (const float*)d_in[1];
    const float* g_b  = (const float*)d_in[2];
    const float* th_w = (const float*)d_in[3];
    const float* th_b = (const float*)d_in[4];
    const float* ph_w = (const float*)d_in[5];
    const float* ph_b = (const float*)d_in[6];
    const float* W_w  = (const float*)d_in[7];
    const float* W_b  = (const float*)d_in[8];
    const float* bn_g = (const float*)d_in[9];
    const float* bn_b = (const float*)d_in[10];
    float* out = (float*)d_out;

    // Workspace: thetaT@0, phiT@4M, gBlk@8M, gT@12M, xT@16M(8M).
    // yPart@12M (over dead gT/xT): 32MB (8-chunk, needs ws>=46.93MB) or 16MB (4-chunk).
    // After attn: yT@0 (over thetaT), Wy@4M..20M (over phiT/gBlk/yPart-head).
    char* ws = (char*)d_ws;
    const size_t MB = 1u << 20;
    __bf16* thetaT = (__bf16*)(ws);
    __bf16* phiT   = (__bf16*)(ws + 4 * MB);
    __bf16* gBlk   = (__bf16*)(ws + 8 * MB);
    __bf16* gT     = (__bf16*)(ws + 12 * MB);
    __bf16* xT     = (__bf16*)(ws + 16 * MB);
    __bf16* yPart  = (__bf16*)(ws + 12 * MB);
    __bf16* yT     = (__bf16*)(ws);
    float*  Wy     = (float*) (ws + 4 * MB);

    const bool big = ws_size >= 46926848ull;
    const size_t tail = big ? 44 * MB : 28 * MB;
    float*  lPart = (float*) (ws + tail);                     // 512K / 256K
    __bf16* wbf   = (__bf16*)(ws + tail + (big ? 524288 : 262144));
    float*  stats = (float*) (ws + tail + (big ? 786432 : 524288));

    prep_w<<<dim3(128), 256, 0, stream>>>(th_w, ph_w, g_w, W_w, wbf);
    xT_kernel<<<dim3(64, 4, 4), 256, 0, stream>>>(x, xT);
    proj_mfma<<<dim3(64, 3, 4), 256, 0, stream>>>(
        xT, wbf, th_b, ph_b, g_b, thetaT, phiT, gT);
    transpose_g<<<dim3(64, 2, 4), 256, 0, stream>>>(gT, gBlk);
    if (big) {
        attn_kernel<8><<<dim3(1024), 256, 0, stream>>>(thetaT, phiT, gBlk, yPart, lPart);
        merge_kernel<8><<<dim3(2048), 256, 0, stream>>>(yPart, lPart, yT);
    } else {
        attn_kernel<4><<<dim3(512), 256, 0, stream>>>(thetaT, phiT, gBlk, yPart, lPart);
        merge_kernel<4><<<dim3(2048), 256, 0, stream>>>(yPart, lPart, yT);
    }
    wy_mfma<<<dim3(32, 4), 256, 0, stream>>>(yT, wbf + 98304, W_b, Wy);
    stats_kernel<<<dim3(256), 256, 0, stream>>>(Wy, bn_g, bn_b, stats);
    final_kernel<<<dim3(4096), 256, 0, stream>>>(Wy, x, stats, out);
}

// Round 7
// 121.869 us; speedup vs baseline: 1.2694x; 1.2694x over previous
//
#include <hip/hip_runtime.h>
#include <hip/hip_bf16.h>

typedef __attribute__((ext_vector_type(8))) __bf16 bf16x8;
typedef __attribute__((ext_vector_type(4))) __bf16 bf16x4;
typedef __attribute__((ext_vector_type(4))) float  f32x4;

#define L2E 1.44269504088896340736f

static __device__ __forceinline__ f32x4 mfma16(bf16x8 a, bf16x8 b, f32x4 c) {
    return __builtin_amdgcn_mfma_f32_16x16x32_bf16(a, b, c, 0, 0, 0);
}

#define GLOAD_LDS16(gsrc, ldst)                                                \
    __builtin_amdgcn_global_load_lds(                                          \
        (const __attribute__((address_space(1))) unsigned int*)(gsrc),         \
        (__attribute__((address_space(3))) unsigned int*)(ldst), 16, 0, 0)

// ---------------- Weight prep: th_w, ph_w, g_w [128x256], W_w [256x128] -> bf16 -------------
__global__ __launch_bounds__(256) void prep_w(
    const float* __restrict__ thw, const float* __restrict__ phw,
    const float* __restrict__ gw,  const float* __restrict__ Ww,
    __bf16* __restrict__ wbf)
{
    const int idx  = blockIdx.x * 256 + threadIdx.x;
    const int base = idx * 4;
    const float* src = (base < 32768) ? thw : (base < 65536) ? phw
                     : (base < 98304) ? gw  : Ww;
    const int off = base & 32767;
    f32x4 v = *reinterpret_cast<const f32x4*>(src + off);
    bf16x4 o;
    #pragma unroll
    for (int i = 0; i < 4; ++i) o[i] = (__bf16)v[i];
    *reinterpret_cast<bf16x4*>(wbf + base) = o;
}

// ---------------- x [B,C,N] f32 -> xT [B,N,256] bf16 ----------------------------------------
__global__ __launch_bounds__(256) void xT_kernel(
    const float* __restrict__ x, __bf16* __restrict__ xT)
{
    __shared__ float tile[64][65];
    const int b  = blockIdx.z;
    const int c0 = blockIdx.y * 64;
    const int n0 = blockIdx.x * 64;
    const int tr = threadIdx.x >> 4;
    const int tc = threadIdx.x & 15;
    #pragma unroll
    for (int k = 0; k < 4; ++k) {
        int c = k * 16 + tr;
        f32x4 v = *reinterpret_cast<const f32x4*>(
            x + ((size_t)b * 256 + c0 + c) * 4096 + n0 + tc * 4);
        #pragma unroll
        for (int i = 0; i < 4; ++i) tile[c][tc * 4 + i] = v[i];
    }
    __syncthreads();
    #pragma unroll
    for (int k = 0; k < 4; ++k) {
        int n = k * 16 + tr;
        bf16x4 v;
        #pragma unroll
        for (int i = 0; i < 4; ++i) v[i] = (__bf16)tile[tc * 4 + i][n];
        *reinterpret_cast<bf16x4*>(xT + ((size_t)b * 4096 + n0 + n) * 256 + c0 + tc * 4) = v;
    }
}

// ---------------- proj MFMA: out[b,n,o] = sum_c xT[b,n,c] w[o,c] + bias[o], bf16 ------------
__global__ __launch_bounds__(256, 1) void proj_mfma(
    const __bf16* __restrict__ xT, const __bf16* __restrict__ wbf,
    const float* __restrict__ bth, const float* __restrict__ bph,
    const float* __restrict__ bg,
    __bf16* __restrict__ thetaT, __bf16* __restrict__ phiT, __bf16* __restrict__ gT)
{
    const int p    = blockIdx.y;
    const int b    = blockIdx.z;
    const int n0   = blockIdx.x * 64;
    const int w    = threadIdx.x >> 6;
    const int lane = threadIdx.x & 63;
    const int lo   = lane & 15;
    const int hi   = lane >> 4;

    __shared__ alignas(16) __bf16 XA[64 * 256];
    __shared__ alignas(16) __bf16 WL[128 * 256];

    const __bf16* wsrc  = wbf + p * 32768;
    const float*  bias  = (p == 0) ? bth : (p == 1) ? bph : bg;
    __bf16*       out   = (p == 0) ? thetaT : (p == 1) ? phiT : gT;
    const __bf16* xbase = xT + ((size_t)b * 4096 + n0) * 256;

    #pragma unroll
    for (int u = 0; u < 8; ++u) {
        const int chunk = (w * 8 + u) * 64 + lane;
        const int row   = chunk >> 5;
        const int jb    = (chunk & 31) * 16;
        const int sb    = row * 512 + (jb ^ ((row & 7) << 4));
        GLOAD_LDS16(xbase + (sb >> 1), &XA[(w * 8 + u) * 512]);
    }
    #pragma unroll
    for (int u = 0; u < 16; ++u) {
        const int chunk = (w * 16 + u) * 64 + lane;
        const int row   = chunk >> 5;
        const int jb    = (chunk & 31) * 16;
        const int sb    = row * 512 + (jb ^ ((row & 7) << 4));
        GLOAD_LDS16(wsrc + (sb >> 1), &WL[(w * 16 + u) * 512]);
    }
    __syncthreads();

    f32x4 C[8];
    #pragma unroll
    for (int cc = 0; cc < 8; ++cc) C[cc] = f32x4{0.f, 0.f, 0.f, 0.f};

    const int arow = w * 16 + lo;
    #pragma unroll
    for (int kb = 0; kb < 8; ++kb) {
        const int koff = kb * 64 + hi * 16;
        bf16x8 a = *reinterpret_cast<const bf16x8*>(
            (const char*)XA + arow * 512 + (koff ^ ((arow & 7) << 4)));
        bf16x8 bb[8];
        #pragma unroll
        for (int cc = 0; cc < 8; ++cc) {
            const int o = cc * 16 + lo;
            bb[cc] = *reinterpret_cast<const bf16x8*>(
                (const char*)WL + o * 512 + (koff ^ ((o & 7) << 4)));
        }
        #pragma unroll
        for (int cc = 0; cc < 8; ++cc) C[cc] = mfma16(a, bb[cc], C[cc]);
    }

    const int nbase = n0 + w * 16;
    #pragma unroll
    for (int cc = 0; cc < 8; ++cc) {
        const float bv = bias[cc * 16 + lo];
        #pragma unroll
        for (int r = 0; r < 4; ++r)
            out[((size_t)b * 4096 + nbase + 4 * hi + r) * 128 + cc * 16 + lo] =
                (__bf16)(C[cc][r] + bv);
    }
}

// ---------------- Transpose gT [B,N,128] -> blocked gBlk[b][mt][c][32] (bf16) ---------------
__global__ __launch_bounds__(256) void transpose_g(
    const __bf16* __restrict__ gT, __bf16* __restrict__ gBlk)
{
    __shared__ __bf16 tile[64][66];
    const int b  = blockIdx.z;
    const int c0 = blockIdx.y * 64;
    const int n0 = blockIdx.x * 64;
    const int tr = threadIdx.x >> 4;
    const int tc = threadIdx.x & 15;
    #pragma unroll
    for (int k = 0; k < 4; ++k) {
        int row = k * 16 + tr;
        bf16x4 v = *reinterpret_cast<const bf16x4*>(
            gT + ((size_t)b * 4096 + n0 + row) * 128 + c0 + tc * 4);
        #pragma unroll
        for (int i = 0; i < 4; ++i) tile[row][tc * 4 + i] = v[i];
    }
    __syncthreads();
    #pragma unroll
    for (int k = 0; k < 4; ++k) {
        int c = k * 16 + tr;
        int n = n0 + tc * 4;
        int mt = n >> 5, mm = n & 31;
        bf16x4 v;
        #pragma unroll
        for (int i = 0; i < 4; ++i) v[i] = tile[tc * 4 + i][c];
        *reinterpret_cast<bf16x4*>(
            gBlk + (((size_t)(b * 128 + mt) * 128) + (c0 + c)) * 32 + mm) = v;
    }
}

// ---------------- Flash attention (no-max softmax), LDS-staged KV, KV-split xNCH ------------
// EXACT round-5 body (proven 54us at NCH=4): 4 waves/block, 32 q/wave, per-wave 32-row
// P buffer (80B rows). Only changes: NCH template (8 when ws allows) + launch_bounds(256,3)
// (regs ~80 VGPR + ~64 AGPR = 144 <= 170 cap -> no spill; LDS 43008B -> 3 blocks/CU).
template<int NCH>
__global__ __launch_bounds__(256, 3) void attn_kernel(
    const __bf16* __restrict__ thetaT, const __bf16* __restrict__ phiT,
    const __bf16* __restrict__ gBlk, __bf16* __restrict__ yPart,
    float* __restrict__ lPart)
{
    constexpr int SH = (NCH == 8) ? 3 : 2;
    constexpr int NT = (4096 / NCH) / 32;
    const int bid   = blockIdx.x;
    const int chunk = bid & (NCH - 1);
    const int qb    = (bid >> SH) & 31;
    const int b     = bid >> (SH + 5);
    const int w     = threadIdx.x >> 6;
    const int lane  = threadIdx.x & 63;
    const int lo    = lane & 15;
    const int hi    = lane >> 4;
    const int Q0    = qb * 128 + w * 32;
    const int kvbase = chunk * (4096 / NCH);

    __shared__ alignas(16) __bf16 Kt[2][32 * 128];
    __shared__ alignas(16) __bf16 Vt[2][128 * 32];
    __shared__ alignas(16) __bf16 plds[4][32 * 40];   // per-wave 32-row P tile, 80B rows

    bf16x8 qf[2][4];
    #pragma unroll
    for (int qq = 0; qq < 2; ++qq) {
        const size_t qrow = ((size_t)b * 4096 + Q0 + qq * 16 + lo) * 128 + hi * 8;
        #pragma unroll
        for (int kb = 0; kb < 4; ++kb)
            qf[qq][kb] = *reinterpret_cast<const bf16x8*>(thetaT + qrow + kb * 32);
    }

    f32x4 yacc[2][8], yl[2];
    #pragma unroll
    for (int qq = 0; qq < 2; ++qq) {
        yl[qq] = f32x4{0.f, 0.f, 0.f, 0.f};
        #pragma unroll
        for (int cc = 0; cc < 8; ++cc) yacc[qq][cc] = f32x4{0.f, 0.f, 0.f, 0.f};
    }
    bf16x8 onesf;
    #pragma unroll
    for (int e = 0; e < 8; ++e) onesf[e] = (__bf16)1.0f;

    const __bf16* phiB   = phiT + (size_t)b * 4096 * 128;
    const __bf16* gBlk_b = gBlk + (size_t)b * 128 * 4096;
    __bf16* pw = &plds[w][0];

    auto stage = [&](int buf, int t) {
        const int kv = kvbase + t * 32;
        #pragma unroll
        for (int u = 0; u < 2; ++u) {
            const int ii   = w + u * 4;
            const int mrow = ii * 4 + (lane >> 4);
            const int cbl  = ((lane & 15) * 16) ^ ((mrow & 7) << 4);
            const __bf16* src = phiB + ((size_t)(kv + mrow) << 7) + (cbl >> 1);
            GLOAD_LDS16(src, &Kt[buf][ii * 512]);
        }
        const __bf16* vtile = gBlk_b + ((size_t)(kv >> 5) << 12);
        #pragma unroll
        for (int u = 0; u < 2; ++u) {
            const int jj = w + u * 4;
            const int ch = jj * 64 + lane;
            const int c  = ch >> 2;
            const int h  = (ch & 3) ^ (c & 3);
            const __bf16* src = vtile + c * 32 + h * 8;
            GLOAD_LDS16(src, &Vt[buf][jj * 512]);
        }
    };

    stage(0, 0);

    #pragma unroll 1
    for (int t = 0; t < NT; ++t) {
        const int cur = t & 1;
        if (t < NT - 1) {
            stage(cur ^ 1, t + 1);
            asm volatile("s_waitcnt vmcnt(4)" ::: "memory");
        } else {
            asm volatile("s_waitcnt vmcnt(0)" ::: "memory");
        }
        __builtin_amdgcn_s_barrier();
        __builtin_amdgcn_sched_barrier(0);

        const __bf16* Kb = &Kt[cur][0];
        const __bf16* Vb = &Vt[cur][0];

        f32x4 f0[2], f1[2];
        f0[0] = f0[1] = f1[0] = f1[1] = f32x4{0.f, 0.f, 0.f, 0.f};
        #pragma unroll
        for (int kb = 0; kb < 4; ++kb) {
            const int cb = (kb * 64 + hi * 16) ^ ((lo & 7) << 4);
            bf16x8 b0 = *reinterpret_cast<const bf16x8*>(Kb + lo * 128 + (cb >> 1));
            bf16x8 b1 = *reinterpret_cast<const bf16x8*>(Kb + (16 + lo) * 128 + (cb >> 1));
            #pragma unroll
            for (int qq = 0; qq < 2; ++qq) {
                f0[qq] = mfma16(qf[qq][kb], b0, f0[qq]);
                f1[qq] = mfma16(qf[qq][kb], b1, f1[qq]);
            }
        }

        #pragma unroll
        for (int qq = 0; qq < 2; ++qq)
            #pragma unroll
            for (int r = 0; r < 4; ++r) {
                float p0 = __builtin_amdgcn_exp2f(f0[qq][r] * L2E);
                float p1 = __builtin_amdgcn_exp2f(f1[qq][r] * L2E);
                const int nrow = qq * 16 + 4 * hi + r;
                pw[nrow * 40 + lo]      = (__bf16)p0;
                pw[nrow * 40 + 16 + lo] = (__bf16)p1;
            }
        bf16x8 pa0 = *reinterpret_cast<const bf16x8*>(pw + lo * 40 + hi * 8);
        bf16x8 pa1 = *reinterpret_cast<const bf16x8*>(pw + (16 + lo) * 40 + hi * 8);

        yl[0] = mfma16(pa0, onesf, yl[0]);
        yl[1] = mfma16(pa1, onesf, yl[1]);
        #pragma unroll
        for (int cc = 0; cc < 8; ++cc) {
            const int vr = cc * 16 + lo;
            bf16x8 gb = *reinterpret_cast<const bf16x8*>(
                Vb + vr * 32 + ((hi ^ (vr & 3)) * 8));
            yacc[0][cc] = mfma16(pa0, gb, yacc[0][cc]);
            yacc[1][cc] = mfma16(pa1, gb, yacc[1][cc]);
        }

        asm volatile("" ::: "memory");
        __builtin_amdgcn_s_barrier();
        __builtin_amdgcn_sched_barrier(0);
    }

    const int bc = chunk * 4 + b;
    #pragma unroll
    for (int qq = 0; qq < 2; ++qq)
        #pragma unroll
        for (int r = 0; r < 4; ++r) {
            const int row = Q0 + qq * 16 + 4 * hi + r;
            const size_t base = ((size_t)bc * 4096 + row) * 128;
            #pragma unroll
            for (int cc = 0; cc < 8; ++cc)
                yPart[base + cc * 16 + lo] = (__bf16)yacc[qq][cc][r];
            if (lo == 0)
                lPart[(size_t)bc * 4096 + row] = yl[qq][r];
        }
}

// ---------------- Merge the NC KV-chunk partials: yT = sum(y_c)/sum(l_c), bf16 --------------
template<int NC>
__global__ __launch_bounds__(256) void merge_kernel(
    const __bf16* __restrict__ yPart, const float* __restrict__ lPart,
    __bf16* __restrict__ yT)
{
    const int idx = blockIdx.x * 256 + threadIdx.x;  // 524288 total
    const int row = idx >> 5;
    const int c4  = (idx & 31) * 4;
    float lsum = 0.f;
    #pragma unroll
    for (int c = 0; c < NC; ++c) lsum += lPart[(size_t)c * 16384 + row];
    const float inv = 1.0f / lsum;
    float s[4] = {0.f, 0.f, 0.f, 0.f};
    #pragma unroll
    for (int c = 0; c < NC; ++c) {
        bf16x4 v = *reinterpret_cast<const bf16x4*>(
            yPart + (size_t)c * 2097152 + (size_t)row * 128 + c4);
        #pragma unroll
        for (int i = 0; i < 4; ++i) s[i] += (float)v[i];
    }
    bf16x4 o;
    #pragma unroll
    for (int i = 0; i < 4; ++i) o[i] = (__bf16)(s[i] * inv);
    *reinterpret_cast<bf16x4*>(yT + (size_t)row * 128 + c4) = o;
}

// ---------------- wy MFMA: Wy[b,o,n] = sum_ci Wbf[o,ci] yT[b,n,ci] + Wb[o], f32 -------------
__global__ __launch_bounds__(256, 1) void wy_mfma(
    const __bf16* __restrict__ yT, const __bf16* __restrict__ wW,
    const float* __restrict__ Wb, float* __restrict__ Wy)
{
    const int b    = blockIdx.y;
    const int n0   = blockIdx.x * 128;
    const int w    = threadIdx.x >> 6;
    const int lane = threadIdx.x & 63;
    const int lo   = lane & 15;
    const int hi   = lane >> 4;

    __shared__ alignas(16) __bf16 YL[128 * 128];
    __shared__ alignas(16) __bf16 WL[256 * 128];

    const __bf16* ybase = yT + ((size_t)b * 4096 + n0) * 128;
    #pragma unroll
    for (int u = 0; u < 8; ++u) {
        const int chunk = (w * 8 + u) * 64 + lane;
        const int row   = chunk >> 4;
        const int jb    = (chunk & 15) * 16;
        const int sb    = row * 256 + (jb ^ ((row & 7) << 4));
        GLOAD_LDS16(ybase + (sb >> 1), &YL[(w * 8 + u) * 512]);
    }
    #pragma unroll
    for (int u = 0; u < 16; ++u) {
        const int chunk = (w * 16 + u) * 64 + lane;
        const int row   = chunk >> 4;
        const int jb    = (chunk & 15) * 16;
        const int sb    = row * 256 + (jb ^ ((row & 7) << 4));
        GLOAD_LDS16(wW + (sb >> 1), &WL[(w * 16 + u) * 512]);
    }
    __syncthreads();

    f32x4 C[4][8];
    #pragma unroll
    for (int og = 0; og < 4; ++og)
        #pragma unroll
        for (int ct = 0; ct < 8; ++ct) C[og][ct] = f32x4{0.f, 0.f, 0.f, 0.f};

    #pragma unroll
    for (int kb = 0; kb < 4; ++kb) {
        const int koff = kb * 64 + hi * 16;
        bf16x8 a[4], bb[8];
        #pragma unroll
        for (int og = 0; og < 4; ++og) {
            const int o = w * 64 + og * 16 + lo;
            a[og] = *reinterpret_cast<const bf16x8*>(
                (const char*)WL + o * 256 + (koff ^ ((o & 7) << 4)));
        }
        #pragma unroll
        for (int ct = 0; ct < 8; ++ct) {
            const int nl = ct * 16 + lo;
            bb[ct] = *reinterpret_cast<const bf16x8*>(
                (const char*)YL + nl * 256 + (koff ^ ((nl & 7) << 4)));
        }
        #pragma unroll
        for (int og = 0; og < 4; ++og)
            #pragma unroll
            for (int ct = 0; ct < 8; ++ct)
                C[og][ct] = mfma16(a[og], bb[ct], C[og][ct]);
    }

    #pragma unroll
    for (int og = 0; og < 4; ++og)
        #pragma unroll
        for (int r = 0; r < 4; ++r) {
            const int o  = w * 64 + og * 16 + 4 * hi + r;
            const float bv = Wb[o];
            #pragma unroll
            for (int ct = 0; ct < 8; ++ct)
                Wy[((size_t)b * 256 + o) * 4096 + n0 + ct * 16 + lo] = C[og][ct][r] + bv;
        }
}

// ---------------- Per-channel BN stats over (B, N) ------------------------------------------
__global__ __launch_bounds__(256) void stats_kernel(
    const float* __restrict__ Wy, const float* __restrict__ gamma,
    const float* __restrict__ beta, float* __restrict__ stats)
{
    const int o = blockIdx.x;
    float s = 0.f, q = 0.f;
    for (int i = threadIdx.x; i < 16384; i += 256) {
        int b = i >> 12, n = i & 4095;
        float v = Wy[((size_t)b * 256 + o) * 4096 + n];
        s += v; q += v * v;
    }
    #pragma unroll
    for (int off = 32; off >= 1; off >>= 1) {
        s += __shfl_down(s, off);
        q += __shfl_down(q, off);
    }
    __shared__ float red[8];
    const int wid = threadIdx.x >> 6;
    if ((threadIdx.x & 63) == 0) { red[wid] = s; red[4 + wid] = q; }
    __syncthreads();
    if (threadIdx.x == 0) {
        float S = red[0] + red[1] + red[2] + red[3];
        float Q = red[4] + red[5] + red[6] + red[7];
        float mean = S * (1.f / 16384.f);
        float var  = Q * (1.f / 16384.f) - mean * mean;
        float scl  = gamma[o] * rsqrtf(var + 1e-5f);
        stats[o]       = scl;
        stats[256 + o] = beta[o] - mean * scl;
    }
}

// ---------------- out = Wy*scale + shift + x ------------------------------------------------
__global__ __launch_bounds__(256) void final_kernel(
    const float* __restrict__ Wy, const float* __restrict__ x,
    const float* __restrict__ stats, float* __restrict__ out)
{
    const int idx = blockIdx.x * 256 + threadIdx.x;
    const int o   = (idx >> 10) & 255;
    f32x4 wy = *reinterpret_cast<const f32x4*>(Wy + (size_t)idx * 4);
    f32x4 xv = *reinterpret_cast<const f32x4*>(x  + (size_t)idx * 4);
    f32x4 res = wy * stats[o] + stats[256 + o] + xv;
    *reinterpret_cast<f32x4*>(out + (size_t)idx * 4) = res;
}

extern "C" void kernel_launch(void* const* d_in, const int* in_sizes, int n_in,
                              void* d_out, int out_size, void* d_ws, size_t ws_size,
                              hipStream_t stream)
{
    const float* x    = (const float*)d_in[0];
    const float* g_w  = (const float*)d_in[1];
    const float* g_b  = (const float*)d_in[2];
    const float* th_w = (const float*)d_in[3];
    const float* th_b = (const float*)d_in[4];
    const float* ph_w = (const float*)d_in[5];
    const float* ph_b = (const float*)d_in[6];
    const float* W_w  = (const float*)d_in[7];
    const float* W_b  = (const float*)d_in[8];
    const float* bn_g = (const float*)d_in[9];
    const float* bn_b = (const float*)d_in[10];
    float* out = (float*)d_out;

    // Workspace: thetaT@0, phiT@4M, gBlk@8M, gT@12M, xT@16M(8M).
    // yPart@12M (over dead gT/xT): 32MB (8-chunk, needs ws>=46.93MB) or 16MB (4-chunk).
    // After attn: yT@0 (over thetaT), Wy@4M..20M (over phiT/gBlk/yPart-head).
    char* ws = (char*)d_ws;
    const size_t MB = 1u << 20;
    __bf16* thetaT = (__bf16*)(ws);
    __bf16* phiT   = (__bf16*)(ws + 4 * MB);
    __bf16* gBlk   = (__bf16*)(ws + 8 * MB);
    __bf16* gT     = (__bf16*)(ws + 12 * MB);
    __bf16* xT     = (__bf16*)(ws + 16 * MB);
    __bf16* yPart  = (__bf16*)(ws + 12 * MB);
    __bf16* yT     = (__bf16*)(ws);
    float*  Wy     = (float*) (ws + 4 * MB);

    const bool big = ws_size >= 46926848ull;
    const size_t tail = big ? 44 * MB : 28 * MB;
    float*  lPart = (float*) (ws + tail);                     // 512K / 256K
    __bf16* wbf   = (__bf16*)(ws + tail + (big ? 524288 : 262144));
    float*  stats = (float*) (ws + tail + (big ? 786432 : 524288));

    prep_w<<<dim3(128), 256, 0, stream>>>(th_w, ph_w, g_w, W_w, wbf);
    xT_kernel<<<dim3(64, 4, 4), 256, 0, stream>>>(x, xT);
    proj_mfma<<<dim3(64, 3, 4), 256, 0, stream>>>(
        xT, wbf, th_b, ph_b, g_b, thetaT, phiT, gT);
    transpose_g<<<dim3(64, 2, 4), 256, 0, stream>>>(gT, gBlk);
    if (big) {
        attn_kernel<8><<<dim3(1024), 256, 0, stream>>>(thetaT, phiT, gBlk, yPart, lPart);
        merge_kernel<8><<<dim3(2048), 256, 0, stream>>>(yPart, lPart, yT);
    } else {
        attn_kernel<4><<<dim3(512), 256, 0, stream>>>(thetaT, phiT, gBlk, yPart, lPart);
        merge_kernel<4><<<dim3(2048), 256, 0, stream>>>(yPart, lPart, yT);
    }
    wy_mfma<<<dim3(32, 4), 256, 0, stream>>>(yT, wbf + 98304, W_b, Wy);
    stats_kernel<<<dim3(256), 256, 0, stream>>>(Wy, bn_g, bn_b, stats);
    final_kernel<<<dim3(4096), 256, 0, stream>>>(Wy, x, stats, out);
}

// Round 8
// 116.045 us; speedup vs baseline: 1.3331x; 1.0502x over previous
//
#include <hip/hip_runtime.h>
#include <hip/hip_bf16.h>

typedef __attribute__((ext_vector_type(8))) __bf16 bf16x8;
typedef __attribute__((ext_vector_type(4))) __bf16 bf16x4;
typedef __attribute__((ext_vector_type(4))) float  f32x4;
typedef __attribute__((ext_vector_type(16))) float f32x16;

#define L2E 1.44269504088896340736f

static __device__ __forceinline__ f32x4 mfma16(bf16x8 a, bf16x8 b, f32x4 c) {
    return __builtin_amdgcn_mfma_f32_16x16x32_bf16(a, b, c, 0, 0, 0);
}
static __device__ __forceinline__ f32x16 mfma32(bf16x8 a, bf16x8 b, f32x16 c) {
    return __builtin_amdgcn_mfma_f32_32x32x16_bf16(a, b, c, 0, 0, 0);
}

#define GLOAD_LDS16(gsrc, ldst)                                                \
    __builtin_amdgcn_global_load_lds(                                          \
        (const __attribute__((address_space(1))) unsigned int*)(gsrc),         \
        (__attribute__((address_space(3))) unsigned int*)(ldst), 16, 0, 0)

// ---------------- Weight prep: th_w, ph_w, g_w [128x256], W_w [256x128] -> bf16 -------------
__global__ __launch_bounds__(256) void prep_w(
    const float* __restrict__ thw, const float* __restrict__ phw,
    const float* __restrict__ gw,  const float* __restrict__ Ww,
    __bf16* __restrict__ wbf)
{
    const int idx  = blockIdx.x * 256 + threadIdx.x;
    const int base = idx * 4;
    const float* src = (base < 32768) ? thw : (base < 65536) ? phw
                     : (base < 98304) ? gw  : Ww;
    const int off = base & 32767;
    f32x4 v = *reinterpret_cast<const f32x4*>(src + off);
    bf16x4 o;
    #pragma unroll
    for (int i = 0; i < 4; ++i) o[i] = (__bf16)v[i];
    *reinterpret_cast<bf16x4*>(wbf + base) = o;
}

// ---------------- x [B,C,N] f32 -> xT [B,N,256] bf16 ----------------------------------------
__global__ __launch_bounds__(256) void xT_kernel(
    const float* __restrict__ x, __bf16* __restrict__ xT)
{
    __shared__ float tile[64][65];
    const int b  = blockIdx.z;
    const int c0 = blockIdx.y * 64;
    const int n0 = blockIdx.x * 64;
    const int tr = threadIdx.x >> 4;
    const int tc = threadIdx.x & 15;
    #pragma unroll
    for (int k = 0; k < 4; ++k) {
        int c = k * 16 + tr;
        f32x4 v = *reinterpret_cast<const f32x4*>(
            x + ((size_t)b * 256 + c0 + c) * 4096 + n0 + tc * 4);
        #pragma unroll
        for (int i = 0; i < 4; ++i) tile[c][tc * 4 + i] = v[i];
    }
    __syncthreads();
    #pragma unroll
    for (int k = 0; k < 4; ++k) {
        int n = k * 16 + tr;
        bf16x4 v;
        #pragma unroll
        for (int i = 0; i < 4; ++i) v[i] = (__bf16)tile[tc * 4 + i][n];
        *reinterpret_cast<bf16x4*>(xT + ((size_t)b * 4096 + n0 + n) * 256 + c0 + tc * 4) = v;
    }
}

// ---------------- proj MFMA: out[b,n,o] = sum_c xT[b,n,c] w[o,c] + bias[o], bf16 ------------
__global__ __launch_bounds__(256, 1) void proj_mfma(
    const __bf16* __restrict__ xT, const __bf16* __restrict__ wbf,
    const float* __restrict__ bth, const float* __restrict__ bph,
    const float* __restrict__ bg,
    __bf16* __restrict__ thetaT, __bf16* __restrict__ phiT, __bf16* __restrict__ gT)
{
    const int p    = blockIdx.y;
    const int b    = blockIdx.z;
    const int n0   = blockIdx.x * 64;
    const int w    = threadIdx.x >> 6;
    const int lane = threadIdx.x & 63;
    const int lo   = lane & 15;
    const int hi   = lane >> 4;

    __shared__ alignas(16) __bf16 XA[64 * 256];
    __shared__ alignas(16) __bf16 WL[128 * 256];

    const __bf16* wsrc  = wbf + p * 32768;
    const float*  bias  = (p == 0) ? bth : (p == 1) ? bph : bg;
    __bf16*       out   = (p == 0) ? thetaT : (p == 1) ? phiT : gT;
    const __bf16* xbase = xT + ((size_t)b * 4096 + n0) * 256;

    #pragma unroll
    for (int u = 0; u < 8; ++u) {
        const int chunk = (w * 8 + u) * 64 + lane;
        const int row   = chunk >> 5;
        const int jb    = (chunk & 31) * 16;
        const int sb    = row * 512 + (jb ^ ((row & 7) << 4));
        GLOAD_LDS16(xbase + (sb >> 1), &XA[(w * 8 + u) * 512]);
    }
    #pragma unroll
    for (int u = 0; u < 16; ++u) {
        const int chunk = (w * 16 + u) * 64 + lane;
        const int row   = chunk >> 5;
        const int jb    = (chunk & 31) * 16;
        const int sb    = row * 512 + (jb ^ ((row & 7) << 4));
        GLOAD_LDS16(wsrc + (sb >> 1), &WL[(w * 16 + u) * 512]);
    }
    __syncthreads();

    f32x4 C[8];
    #pragma unroll
    for (int cc = 0; cc < 8; ++cc) C[cc] = f32x4{0.f, 0.f, 0.f, 0.f};

    const int arow = w * 16 + lo;
    #pragma unroll
    for (int kb = 0; kb < 8; ++kb) {
        const int koff = kb * 64 + hi * 16;
        bf16x8 a = *reinterpret_cast<const bf16x8*>(
            (const char*)XA + arow * 512 + (koff ^ ((arow & 7) << 4)));
        bf16x8 bb[8];
        #pragma unroll
        for (int cc = 0; cc < 8; ++cc) {
            const int o = cc * 16 + lo;
            bb[cc] = *reinterpret_cast<const bf16x8*>(
                (const char*)WL + o * 512 + (koff ^ ((o & 7) << 4)));
        }
        #pragma unroll
        for (int cc = 0; cc < 8; ++cc) C[cc] = mfma16(a, bb[cc], C[cc]);
    }

    const int nbase = n0 + w * 16;
    #pragma unroll
    for (int cc = 0; cc < 8; ++cc) {
        const float bv = bias[cc * 16 + lo];
        #pragma unroll
        for (int r = 0; r < 4; ++r)
            out[((size_t)b * 4096 + nbase + 4 * hi + r) * 128 + cc * 16 + lo] =
                (__bf16)(C[cc][r] + bv);
    }
}

// ---------------- Transpose gT [B,N,128] -> blocked gBlk[b][mt][c][32] (bf16) ---------------
// 4-wide m-groups within each 32-m row are stored permuted [g0,g2,g1,g3,g4,g6,g5,g7] so the
// PV B-fragment's k-order matches the in-register P fragment (see attn_kernel).
__global__ __launch_bounds__(256) void transpose_g(
    const __bf16* __restrict__ gT, __bf16* __restrict__ gBlk)
{
    __shared__ __bf16 tile[64][66];
    const int b  = blockIdx.z;
    const int c0 = blockIdx.y * 64;
    const int n0 = blockIdx.x * 64;
    const int tr = threadIdx.x >> 4;
    const int tc = threadIdx.x & 15;
    #pragma unroll
    for (int k = 0; k < 4; ++k) {
        int row = k * 16 + tr;
        bf16x4 v = *reinterpret_cast<const bf16x4*>(
            gT + ((size_t)b * 4096 + n0 + row) * 128 + c0 + tc * 4);
        #pragma unroll
        for (int i = 0; i < 4; ++i) tile[row][tc * 4 + i] = v[i];
    }
    __syncthreads();
    #pragma unroll
    for (int k = 0; k < 4; ++k) {
        int c = k * 16 + tr;
        int n = n0 + tc * 4;
        int mt = n >> 5, mm = n & 31;
        int g  = mm >> 2;                                   // 4-m group 0..7
        int gp = (g & 4) | ((g & 1) << 1) | ((g >> 1) & 1); // tau: swap bits 0,1
        int mmP = (gp << 2) | (mm & 3);
        bf16x4 v;
        #pragma unroll
        for (int i = 0; i < 4; ++i) v[i] = tile[tc * 4 + i][c];
        *reinterpret_cast<bf16x4*>(
            gBlk + (((size_t)(b * 128 + mt) * 128) + (c0 + c)) * 32 + mmP) = v;
    }
}

// ---------------- Flash attention: 32x32 swapped-QK, fully in-register P --------------------
// 4 waves/block, 32 q/wave (q = lane&31). QK computed as mfma32(K, Q) so each lane holds
// P[m][q=lane&31] with m = (r&3)+8*(r>>2)+4*(lane>>5). Choosing the PV k-permutation
// pi(k0-7)={0-3,8-11}, pi(k8-15)={4-7,12-15}, pi(k16-23)={16-19,24-27}, pi(k24-31)={20-23,28-31}
// makes the PV A-fragments equal to the C-regs in natural order (pa0=p[0..7], pa1=p[8..15])
// for BOTH lane halves; gBlk's group permutation applies the same pi to V's m-axis.
// No P LDS roundtrip, no cross-lane ops in the loop. l = VALU row-sum + one end shfl.
template<int NCH>
__global__ __launch_bounds__(256, 3) void attn_kernel(
    const __bf16* __restrict__ thetaT, const __bf16* __restrict__ phiT,
    const __bf16* __restrict__ gBlk, __bf16* __restrict__ yPart,
    float* __restrict__ lPart)
{
    constexpr int SH = (NCH == 8) ? 3 : 2;
    constexpr int NT = (4096 / NCH) / 32;
    const int bid   = blockIdx.x;
    const int chunk = bid & (NCH - 1);
    const int qb    = (bid >> SH) & 31;
    const int b     = bid >> (SH + 5);
    const int w     = threadIdx.x >> 6;
    const int lane  = threadIdx.x & 63;
    const int l31   = lane & 31;
    const int h2    = lane >> 5;
    const int Q0    = qb * 128 + w * 32;
    const int kvbase = chunk * (4096 / NCH);

    __shared__ alignas(16) __bf16 Kt[2][32 * 128];   // 16KB, rows m (256B), XOR-swizzled
    __shared__ alignas(16) __bf16 Vt[2][128 * 32];   // 16KB, rows c (64B), chunk^=(c&3)

    // Q as B-fragments (col q = l31, k = channel): 8 frags over c=128
    bf16x8 qf[8];
    {
        const __bf16* qrow = thetaT + ((size_t)b * 4096 + Q0 + l31) * 128 + h2 * 8;
        #pragma unroll
        for (int ks = 0; ks < 8; ++ks)
            qf[ks] = *reinterpret_cast<const bf16x8*>(qrow + ks * 16);
    }

    f32x16 yacc[4];
    #pragma unroll
    for (int ct = 0; ct < 4; ++ct)
        #pragma unroll
        for (int r = 0; r < 16; ++r) yacc[ct][r] = 0.f;
    float ylrun = 0.f;

    const __bf16* phiB   = phiT + (size_t)b * 4096 * 128;
    const __bf16* gBlk_b = gBlk + (size_t)b * 128 * 4096;

    auto stage = [&](int buf, int t) {
        const int kv = kvbase + t * 32;
        #pragma unroll
        for (int u = 0; u < 2; ++u) {
            const int ii   = w + u * 4;
            const int mrow = ii * 4 + (lane >> 4);
            const int cbl  = ((lane & 15) * 16) ^ ((mrow & 7) << 4);
            const __bf16* src = phiB + ((size_t)(kv + mrow) << 7) + (cbl >> 1);
            GLOAD_LDS16(src, &Kt[buf][ii * 512]);
        }
        const __bf16* vtile = gBlk_b + ((size_t)(kv >> 5) << 12);
        #pragma unroll
        for (int u = 0; u < 2; ++u) {
            const int jj = w + u * 4;
            const int ch = jj * 64 + lane;
            const int c  = ch >> 2;
            const int h  = (ch & 3) ^ (c & 3);
            const __bf16* src = vtile + c * 32 + h * 8;
            GLOAD_LDS16(src, &Vt[buf][jj * 512]);
        }
    };

    stage(0, 0);

    #pragma unroll 1
    for (int t = 0; t < NT; ++t) {
        const int cur = t & 1;
        if (t < NT - 1) {
            stage(cur ^ 1, t + 1);
            asm volatile("s_waitcnt vmcnt(4)" ::: "memory");
        } else {
            asm volatile("s_waitcnt vmcnt(0)" ::: "memory");
        }
        __builtin_amdgcn_s_barrier();
        __builtin_amdgcn_sched_barrier(0);

        const char* Kb = (const char*)&Kt[cur][0];
        const char* Vb = (const char*)&Vt[cur][0];

        // QK^T swapped: S[m][q]; A = K rows (from LDS), B = Q (registers)
        f32x16 S;
        #pragma unroll
        for (int r = 0; r < 16; ++r) S[r] = 0.f;
        #pragma unroll
        for (int ks = 0; ks < 8; ++ks) {
            bf16x8 ka = *reinterpret_cast<const bf16x8*>(
                Kb + l31 * 256 + ((ks * 32 + h2 * 16) ^ ((l31 & 7) << 4)));
            S = mfma32(ka, qf[ks], S);
        }

        // P = exp(S) in-register; row-sum for l; pack PV A-frags in natural reg order
        float p[16];
        #pragma unroll
        for (int r = 0; r < 16; ++r) p[r] = __builtin_amdgcn_exp2f(S[r] * L2E);
        float ls = 0.f;
        #pragma unroll
        for (int r = 0; r < 16; ++r) ls += p[r];
        ylrun += ls;
        bf16x8 pa0, pa1;
        #pragma unroll
        for (int e = 0; e < 8; ++e) { pa0[e] = (__bf16)p[e]; pa1[e] = (__bf16)p[8 + e]; }

        // PV: yacc[ct][q][c] += P(32q x 32m) V(32m x 32c); V chunks follow pi via gBlk perm
        #pragma unroll
        for (int ct = 0; ct < 4; ++ct) {
            const int vrow = (ct * 32 + l31) * 64;
            bf16x8 v0 = *reinterpret_cast<const bf16x8*>(
                Vb + vrow + ((h2 ^ (l31 & 3)) << 4));
            bf16x8 v1 = *reinterpret_cast<const bf16x8*>(
                Vb + vrow + (((2 + h2) ^ (l31 & 3)) << 4));
            yacc[ct] = mfma32(pa0, v0, yacc[ct]);
            yacc[ct] = mfma32(pa1, v1, yacc[ct]);
        }

        asm volatile("" ::: "memory");
        __builtin_amdgcn_s_barrier();
        __builtin_amdgcn_sched_barrier(0);
    }

    const float ylt = ylrun + __shfl_xor(ylrun, 32);
    const int bc = chunk * 4 + b;
    #pragma unroll
    for (int ct = 0; ct < 4; ++ct)
        #pragma unroll
        for (int r = 0; r < 16; ++r) {
            const int q = Q0 + (r & 3) + 8 * (r >> 2) + 4 * h2;
            yPart[((size_t)bc * 4096 + q) * 128 + ct * 32 + l31] = (__bf16)yacc[ct][r];
        }
    if (h2 == 0)
        lPart[(size_t)bc * 4096 + Q0 + l31] = ylt;
}

// ---------------- Merge the NC KV-chunk partials: yT = sum(y_c)/sum(l_c), bf16 --------------
template<int NC>
__global__ __launch_bounds__(256) void merge_kernel(
    const __bf16* __restrict__ yPart, const float* __restrict__ lPart,
    __bf16* __restrict__ yT)
{
    const int idx = blockIdx.x * 256 + threadIdx.x;  // 524288 total
    const int row = idx >> 5;
    const int c4  = (idx & 31) * 4;
    float lsum = 0.f;
    #pragma unroll
    for (int c = 0; c < NC; ++c) lsum += lPart[(size_t)c * 16384 + row];
    const float inv = 1.0f / lsum;
    float s[4] = {0.f, 0.f, 0.f, 0.f};
    #pragma unroll
    for (int c = 0; c < NC; ++c) {
        bf16x4 v = *reinterpret_cast<const bf16x4*>(
            yPart + (size_t)c * 2097152 + (size_t)row * 128 + c4);
        #pragma unroll
        for (int i = 0; i < 4; ++i) s[i] += (float)v[i];
    }
    bf16x4 o;
    #pragma unroll
    for (int i = 0; i < 4; ++i) o[i] = (__bf16)(s[i] * inv);
    *reinterpret_cast<bf16x4*>(yT + (size_t)row * 128 + c4) = o;
}

// ---------------- wy MFMA: Wy[b,o,n] = sum_ci Wbf[o,ci] yT[b,n,ci] + Wb[o], f32 -------------
__global__ __launch_bounds__(256, 1) void wy_mfma(
    const __bf16* __restrict__ yT, const __bf16* __restrict__ wW,
    const float* __restrict__ Wb, float* __restrict__ Wy)
{
    const int b    = blockIdx.y;
    const int n0   = blockIdx.x * 128;
    const int w    = threadIdx.x >> 6;
    const int lane = threadIdx.x & 63;
    const int lo   = lane & 15;
    const int hi   = lane >> 4;

    __shared__ alignas(16) __bf16 YL[128 * 128];
    __shared__ alignas(16) __bf16 WL[256 * 128];

    const __bf16* ybase = yT + ((size_t)b * 4096 + n0) * 128;
    #pragma unroll
    for (int u = 0; u < 8; ++u) {
        const int chunk = (w * 8 + u) * 64 + lane;
        const int row   = chunk >> 4;
        const int jb    = (chunk & 15) * 16;
        const int sb    = row * 256 + (jb ^ ((row & 7) << 4));
        GLOAD_LDS16(ybase + (sb >> 1), &YL[(w * 8 + u) * 512]);
    }
    #pragma unroll
    for (int u = 0; u < 16; ++u) {
        const int chunk = (w * 16 + u) * 64 + lane;
        const int row   = chunk >> 4;
        const int jb    = (chunk & 15) * 16;
        const int sb    = row * 256 + (jb ^ ((row & 7) << 4));
        GLOAD_LDS16(wW + (sb >> 1), &WL[(w * 16 + u) * 512]);
    }
    __syncthreads();

    f32x4 C[4][8];
    #pragma unroll
    for (int og = 0; og < 4; ++og)
        #pragma unroll
        for (int ct = 0; ct < 8; ++ct) C[og][ct] = f32x4{0.f, 0.f, 0.f, 0.f};

    #pragma unroll
    for (int kb = 0; kb < 4; ++kb) {
        const int koff = kb * 64 + hi * 16;
        bf16x8 a[4], bb[8];
        #pragma unroll
        for (int og = 0; og < 4; ++og) {
            const int o = w * 64 + og * 16 + lo;
            a[og] = *reinterpret_cast<const bf16x8*>(
                (const char*)WL + o * 256 + (koff ^ ((o & 7) << 4)));
        }
        #pragma unroll
        for (int ct = 0; ct < 8; ++ct) {
            const int nl = ct * 16 + lo;
            bb[ct] = *reinterpret_cast<const bf16x8*>(
                (const char*)YL + nl * 256 + (koff ^ ((nl & 7) << 4)));
        }
        #pragma unroll
        for (int og = 0; og < 4; ++og)
            #pragma unroll
            for (int ct = 0; ct < 8; ++ct)
                C[og][ct] = mfma16(a[og], bb[ct], C[og][ct]);
    }

    #pragma unroll
    for (int og = 0; og < 4; ++og)
        #pragma unroll
        for (int r = 0; r < 4; ++r) {
            const int o  = w * 64 + og * 16 + 4 * hi + r;
            const float bv = Wb[o];
            #pragma unroll
            for (int ct = 0; ct < 8; ++ct)
                Wy[((size_t)b * 256 + o) * 4096 + n0 + ct * 16 + lo] = C[og][ct][r] + bv;
        }
}

// ---------------- Per-channel BN stats over (B, N) ------------------------------------------
__global__ __launch_bounds__(256) void stats_kernel(
    const float* __restrict__ Wy, const float* __restrict__ gamma,
    const float* __restrict__ beta, float* __restrict__ stats)
{
    const int o = blockIdx.x;
    float s = 0.f, q = 0.f;
    for (int i = threadIdx.x; i < 16384; i += 256) {
        int b = i >> 12, n = i & 4095;
        float v = Wy[((size_t)b * 256 + o) * 4096 + n];
        s += v; q += v * v;
    }
    #pragma unroll
    for (int off = 32; off >= 1; off >>= 1) {
        s += __shfl_down(s, off);
        q += __shfl_down(q, off);
    }
    __shared__ float red[8];
    const int wid = threadIdx.x >> 6;
    if ((threadIdx.x & 63) == 0) { red[wid] = s; red[4 + wid] = q; }
    __syncthreads();
    if (threadIdx.x == 0) {
        float S = red[0] + red[1] + red[2] + red[3];
        float Q = red[4] + red[5] + red[6] + red[7];
        float mean = S * (1.f / 16384.f);
        float var  = Q * (1.f / 16384.f) - mean * mean;
        float scl  = gamma[o] * rsqrtf(var + 1e-5f);
        stats[o]       = scl;
        stats[256 + o] = beta[o] - mean * scl;
    }
}

// ---------------- out = Wy*scale + shift + x ------------------------------------------------
__global__ __launch_bounds__(256) void final_kernel(
    const float* __restrict__ Wy, const float* __restrict__ x,
    const float* __restrict__ stats, float* __restrict__ out)
{
    const int idx = blockIdx.x * 256 + threadIdx.x;
    const int o   = (idx >> 10) & 255;
    f32x4 wy = *reinterpret_cast<const f32x4*>(Wy + (size_t)idx * 4);
    f32x4 xv = *reinterpret_cast<const f32x4*>(x  + (size_t)idx * 4);
    f32x4 res = wy * stats[o] + stats[256 + o] + xv;
    *reinterpret_cast<f32x4*>(out + (size_t)idx * 4) = res;
}

extern "C" void kernel_launch(void* const* d_in, const int* in_sizes, int n_in,
                              void* d_out, int out_size, void* d_ws, size_t ws_size,
                              hipStream_t stream)
{
    const float* x    = (const float*)d_in[0];
    const float* g_w  = (const float*)d_in[1];
    const float* g_b  = (const float*)d_in[2];
    const float* th_w = (const float*)d_in[3];
    const float* th_b = (const float*)d_in[4];
    const float* ph_w = (const float*)d_in[5];
    const float* ph_b = (const float*)d_in[6];
    const float* W_w  = (const float*)d_in[7];
    const float* W_b  = (const float*)d_in[8];
    const float* bn_g = (const float*)d_in[9];
    const float* bn_b = (const float*)d_in[10];
    float* out = (float*)d_out;

    // Workspace: thetaT@0, phiT@4M, gBlk@8M, gT@12M, xT@16M(8M).
    // yPart@12M (over dead gT/xT): 32MB (8-chunk, needs ws>=46.93MB) or 16MB (4-chunk).
    // After attn: yT@0 (over thetaT), Wy@4M..20M (over phiT/gBlk/yPart-head).
    char* ws = (char*)d_ws;
    const size_t MB = 1u << 20;
    __bf16* thetaT = (__bf16*)(ws);
    __bf16* phiT   = (__bf16*)(ws + 4 * MB);
    __bf16* gBlk   = (__bf16*)(ws + 8 * MB);
    __bf16* gT     = (__bf16*)(ws + 12 * MB);
    __bf16* xT     = (__bf16*)(ws + 16 * MB);
    __bf16* yPart  = (__bf16*)(ws + 12 * MB);
    __bf16* yT     = (__bf16*)(ws);
    float*  Wy     = (float*) (ws + 4 * MB);

    const bool big = ws_size >= 46926848ull;
    const size_t tail = big ? 44 * MB : 28 * MB;
    float*  lPart = (float*) (ws + tail);                     // 512K / 256K
    __bf16* wbf   = (__bf16*)(ws + tail + (big ? 524288 : 262144));
    float*  stats = (float*) (ws + tail + (big ? 786432 : 524288));

    prep_w<<<dim3(128), 256, 0, stream>>>(th_w, ph_w, g_w, W_w, wbf);
    xT_kernel<<<dim3(64, 4, 4), 256, 0, stream>>>(x, xT);
    proj_mfma<<<dim3(64, 3, 4), 256, 0, stream>>>(
        xT, wbf, th_b, ph_b, g_b, thetaT, phiT, gT);
    transpose_g<<<dim3(64, 2, 4), 256, 0, stream>>>(gT, gBlk);
    if (big) {
        attn_kernel<8><<<dim3(1024), 256, 0, stream>>>(thetaT, phiT, gBlk, yPart, lPart);
        merge_kernel<8><<<dim3(2048), 256, 0, stream>>>(yPart, lPart, yT);
    } else {
        attn_kernel<4><<<dim3(512), 256, 0, stream>>>(thetaT, phiT, gBlk, yPart, lPart);
        merge_kernel<4><<<dim3(2048), 256, 0, stream>>>(yPart, lPart, yT);
    }
    wy_mfma<<<dim3(32, 4), 256, 0, stream>>>(yT, wbf + 98304, W_b, Wy);
    stats_kernel<<<dim3(256), 256, 0, stream>>>(Wy, bn_g, bn_b, stats);
    final_kernel<<<dim3(4096), 256, 0, stream>>>(Wy, x, stats, out);
}

// Round 9
// 102.093 us; speedup vs baseline: 1.5153x; 1.1367x over previous
//
#include <hip/hip_runtime.h>
#include <hip/hip_bf16.h>

typedef __attribute__((ext_vector_type(8))) __bf16 bf16x8;
typedef __attribute__((ext_vector_type(4))) __bf16 bf16x4;
typedef __attribute__((ext_vector_type(4))) float  f32x4;
typedef __attribute__((ext_vector_type(16))) float f32x16;

#define L2E 1.44269504088896340736f

static __device__ __forceinline__ f32x4 mfma16(bf16x8 a, bf16x8 b, f32x4 c) {
    return __builtin_amdgcn_mfma_f32_16x16x32_bf16(a, b, c, 0, 0, 0);
}
static __device__ __forceinline__ f32x16 mfma32(bf16x8 a, bf16x8 b, f32x16 c) {
    return __builtin_amdgcn_mfma_f32_32x32x16_bf16(a, b, c, 0, 0, 0);
}

#define GLOAD_LDS16(gsrc, ldst)                                                \
    __builtin_amdgcn_global_load_lds(                                          \
        (const __attribute__((address_space(1))) unsigned int*)(gsrc),         \
        (__attribute__((address_space(3))) unsigned int*)(ldst), 16, 0, 0)

// ---------------- Weight prep: th_w, ph_w, g_w [128x256], W_w [256x128] -> bf16 -------------
__global__ __launch_bounds__(256) void prep_w(
    const float* __restrict__ thw, const float* __restrict__ phw,
    const float* __restrict__ gw,  const float* __restrict__ Ww,
    __bf16* __restrict__ wbf)
{
    const int idx  = blockIdx.x * 256 + threadIdx.x;
    const int base = idx * 4;
    const float* src = (base < 32768) ? thw : (base < 65536) ? phw
                     : (base < 98304) ? gw  : Ww;
    const int off = base & 32767;
    f32x4 v = *reinterpret_cast<const f32x4*>(src + off);
    bf16x4 o;
    #pragma unroll
    for (int i = 0; i < 4; ++i) o[i] = (__bf16)v[i];
    *reinterpret_cast<bf16x4*>(wbf + base) = o;
}

// ---------------- x [B,C,N] f32 -> xT [B,N,256] bf16 ----------------------------------------
__global__ __launch_bounds__(256) void xT_kernel(
    const float* __restrict__ x, __bf16* __restrict__ xT)
{
    __shared__ float tile[64][65];
    const int b  = blockIdx.z;
    const int c0 = blockIdx.y * 64;
    const int n0 = blockIdx.x * 64;
    const int tr = threadIdx.x >> 4;
    const int tc = threadIdx.x & 15;
    #pragma unroll
    for (int k = 0; k < 4; ++k) {
        int c = k * 16 + tr;
        f32x4 v = *reinterpret_cast<const f32x4*>(
            x + ((size_t)b * 256 + c0 + c) * 4096 + n0 + tc * 4);
        #pragma unroll
        for (int i = 0; i < 4; ++i) tile[c][tc * 4 + i] = v[i];
    }
    __syncthreads();
    #pragma unroll
    for (int k = 0; k < 4; ++k) {
        int n = k * 16 + tr;
        bf16x4 v;
        #pragma unroll
        for (int i = 0; i < 4; ++i) v[i] = (__bf16)tile[tc * 4 + i][n];
        *reinterpret_cast<bf16x4*>(xT + ((size_t)b * 4096 + n0 + n) * 256 + c0 + tc * 4) = v;
    }
}

// ---------------- proj MFMA: out[b,n,o] = sum_c xT[b,n,c] w[o,c] + bias[o], bf16 ------------
__global__ __launch_bounds__(256, 1) void proj_mfma(
    const __bf16* __restrict__ xT, const __bf16* __restrict__ wbf,
    const float* __restrict__ bth, const float* __restrict__ bph,
    const float* __restrict__ bg,
    __bf16* __restrict__ thetaT, __bf16* __restrict__ phiT, __bf16* __restrict__ gT)
{
    const int p    = blockIdx.y;
    const int b    = blockIdx.z;
    const int n0   = blockIdx.x * 64;
    const int w    = threadIdx.x >> 6;
    const int lane = threadIdx.x & 63;
    const int lo   = lane & 15;
    const int hi   = lane >> 4;

    __shared__ alignas(16) __bf16 XA[64 * 256];
    __shared__ alignas(16) __bf16 WL[128 * 256];

    const __bf16* wsrc  = wbf + p * 32768;
    const float*  bias  = (p == 0) ? bth : (p == 1) ? bph : bg;
    __bf16*       out   = (p == 0) ? thetaT : (p == 1) ? phiT : gT;
    const __bf16* xbase = xT + ((size_t)b * 4096 + n0) * 256;

    #pragma unroll
    for (int u = 0; u < 8; ++u) {
        const int chunk = (w * 8 + u) * 64 + lane;
        const int row   = chunk >> 5;
        const int jb    = (chunk & 31) * 16;
        const int sb    = row * 512 + (jb ^ ((row & 7) << 4));
        GLOAD_LDS16(xbase + (sb >> 1), &XA[(w * 8 + u) * 512]);
    }
    #pragma unroll
    for (int u = 0; u < 16; ++u) {
        const int chunk = (w * 16 + u) * 64 + lane;
        const int row   = chunk >> 5;
        const int jb    = (chunk & 31) * 16;
        const int sb    = row * 512 + (jb ^ ((row & 7) << 4));
        GLOAD_LDS16(wsrc + (sb >> 1), &WL[(w * 16 + u) * 512]);
    }
    __syncthreads();

    f32x4 C[8];
    #pragma unroll
    for (int cc = 0; cc < 8; ++cc) C[cc] = f32x4{0.f, 0.f, 0.f, 0.f};

    const int arow = w * 16 + lo;
    #pragma unroll
    for (int kb = 0; kb < 8; ++kb) {
        const int koff = kb * 64 + hi * 16;
        bf16x8 a = *reinterpret_cast<const bf16x8*>(
            (const char*)XA + arow * 512 + (koff ^ ((arow & 7) << 4)));
        bf16x8 bb[8];
        #pragma unroll
        for (int cc = 0; cc < 8; ++cc) {
            const int o = cc * 16 + lo;
            bb[cc] = *reinterpret_cast<const bf16x8*>(
                (const char*)WL + o * 512 + (koff ^ ((o & 7) << 4)));
        }
        #pragma unroll
        for (int cc = 0; cc < 8; ++cc) C[cc] = mfma16(a, bb[cc], C[cc]);
    }

    const int nbase = n0 + w * 16;
    #pragma unroll
    for (int cc = 0; cc < 8; ++cc) {
        const float bv = bias[cc * 16 + lo];
        #pragma unroll
        for (int r = 0; r < 4; ++r)
            out[((size_t)b * 4096 + nbase + 4 * hi + r) * 128 + cc * 16 + lo] =
                (__bf16)(C[cc][r] + bv);
    }
}

// ---------------- Transpose gT [B,N,128] -> blocked gBlk[b][mt][c][32] (bf16) ---------------
// 4-wide m-groups permuted [g0,g2,g1,g3,g4,g6,g5,g7] to match the in-register P k-order.
__global__ __launch_bounds__(256) void transpose_g(
    const __bf16* __restrict__ gT, __bf16* __restrict__ gBlk)
{
    __shared__ __bf16 tile[64][66];
    const int b  = blockIdx.z;
    const int c0 = blockIdx.y * 64;
    const int n0 = blockIdx.x * 64;
    const int tr = threadIdx.x >> 4;
    const int tc = threadIdx.x & 15;
    #pragma unroll
    for (int k = 0; k < 4; ++k) {
        int row = k * 16 + tr;
        bf16x4 v = *reinterpret_cast<const bf16x4*>(
            gT + ((size_t)b * 4096 + n0 + row) * 128 + c0 + tc * 4);
        #pragma unroll
        for (int i = 0; i < 4; ++i) tile[row][tc * 4 + i] = v[i];
    }
    __syncthreads();
    #pragma unroll
    for (int k = 0; k < 4; ++k) {
        int c = k * 16 + tr;
        int n = n0 + tc * 4;
        int mt = n >> 5, mm = n & 31;
        int g  = mm >> 2;
        int gp = (g & 4) | ((g & 1) << 1) | ((g >> 1) & 1);
        int mmP = (gp << 2) | (mm & 3);
        bf16x4 v;
        #pragma unroll
        for (int i = 0; i < 4; ++i) v[i] = tile[tc * 4 + i][c];
        *reinterpret_cast<bf16x4*>(
            gBlk + (((size_t)(b * 128 + mt) * 128) + (c0 + c)) * 32 + mmP) = v;
    }
}

// ---------------- Flash attention: 32x32 swapped-QK, in-register P, triple-buffered ---------
// V LDS swizzle h' = h ^ ((c>>1)&3): bank-quad (4c + h') mod 8 distinct across 8-lane phase.
// Prefetch depth 2 (3 buffers), counted vmcnt(8)/(4)/(0) - never drain mid-loop.
template<int NCH>
__global__ __launch_bounds__(256, 3) void attn_kernel(
    const __bf16* __restrict__ thetaT, const __bf16* __restrict__ phiT,
    const __bf16* __restrict__ gBlk, __bf16* __restrict__ yPart,
    float* __restrict__ lPart)
{
    constexpr int SH = (NCH == 8) ? 3 : 2;
    constexpr int NT = (4096 / NCH) / 32;
    const int bid   = blockIdx.x;
    const int chunk = bid & (NCH - 1);
    const int qb    = (bid >> SH) & 31;
    const int b     = bid >> (SH + 5);
    const int w     = threadIdx.x >> 6;
    const int lane  = threadIdx.x & 63;
    const int l31   = lane & 31;
    const int h2    = lane >> 5;
    const int Q0    = qb * 128 + w * 32;
    const int kvbase = chunk * (4096 / NCH);

    __shared__ alignas(16) __bf16 Kt[3][32 * 128];   // 24KB, rows m (256B), XOR-swizzled
    __shared__ alignas(16) __bf16 Vt[3][128 * 32];   // 24KB, rows c (64B), h ^= (c>>1)&3

    bf16x8 qf[8];
    {
        const __bf16* qrow = thetaT + ((size_t)b * 4096 + Q0 + l31) * 128 + h2 * 8;
        #pragma unroll
        for (int ks = 0; ks < 8; ++ks)
            qf[ks] = *reinterpret_cast<const bf16x8*>(qrow + ks * 16);
    }

    f32x16 yacc[4];
    #pragma unroll
    for (int ct = 0; ct < 4; ++ct)
        #pragma unroll
        for (int r = 0; r < 16; ++r) yacc[ct][r] = 0.f;
    float ylrun = 0.f;

    const __bf16* phiB   = phiT + (size_t)b * 4096 * 128;
    const __bf16* gBlk_b = gBlk + (size_t)b * 128 * 4096;

    auto stage = [&](int buf, int t) {
        const int kv = kvbase + t * 32;
        #pragma unroll
        for (int u = 0; u < 2; ++u) {
            const int ii   = w + u * 4;
            const int mrow = ii * 4 + (lane >> 4);
            const int cbl  = ((lane & 15) * 16) ^ ((mrow & 7) << 4);
            const __bf16* src = phiB + ((size_t)(kv + mrow) << 7) + (cbl >> 1);
            GLOAD_LDS16(src, &Kt[buf][ii * 512]);
        }
        const __bf16* vtile = gBlk_b + ((size_t)(kv >> 5) << 12);
        #pragma unroll
        for (int u = 0; u < 2; ++u) {
            const int jj = w + u * 4;
            const int ch = jj * 64 + lane;
            const int c  = ch >> 2;
            const int h  = (ch & 3) ^ ((c >> 1) & 3);   // bank-quad-distinct swizzle
            const __bf16* src = vtile + c * 32 + h * 8;
            GLOAD_LDS16(src, &Vt[buf][jj * 512]);
        }
    };

    stage(0, 0);
    stage(1, 1);

    int ia = 0, ib = 1, ic = 2;
    const int sw = (l31 >> 1) & 3;

    #pragma unroll 1
    for (int t = 0; t < NT; ++t) {
        if (t < NT - 2) {
            stage(ic, t + 2);
            asm volatile("s_waitcnt vmcnt(8)" ::: "memory");
        } else if (t == NT - 2) {
            asm volatile("s_waitcnt vmcnt(4)" ::: "memory");
        } else {
            asm volatile("s_waitcnt vmcnt(0)" ::: "memory");
        }
        __builtin_amdgcn_s_barrier();
        __builtin_amdgcn_sched_barrier(0);

        const char* Kb = (const char*)&Kt[ia][0];
        const char* Vb = (const char*)&Vt[ia][0];

        // QK^T swapped: S[m][q]; A = K rows (LDS), B = Q (registers)
        f32x16 S;
        #pragma unroll
        for (int r = 0; r < 16; ++r) S[r] = 0.f;
        #pragma unroll
        for (int ks = 0; ks < 8; ++ks) {
            bf16x8 ka = *reinterpret_cast<const bf16x8*>(
                Kb + l31 * 256 + ((ks * 32 + h2 * 16) ^ ((l31 & 7) << 4)));
            S = mfma32(ka, qf[ks], S);
        }

        float p[16];
        #pragma unroll
        for (int r = 0; r < 16; ++r) p[r] = __builtin_amdgcn_exp2f(S[r] * L2E);
        float ls = 0.f;
        #pragma unroll
        for (int r = 0; r < 16; ++r) ls += p[r];
        ylrun += ls;
        bf16x8 pa0, pa1;
        #pragma unroll
        for (int e = 0; e < 8; ++e) { pa0[e] = (__bf16)p[e]; pa1[e] = (__bf16)p[8 + e]; }

        #pragma unroll
        for (int ct = 0; ct < 4; ++ct) {
            const int vrow = (ct * 32 + l31) * 64;
            bf16x8 v0 = *reinterpret_cast<const bf16x8*>(
                Vb + vrow + ((h2 ^ sw) << 4));
            bf16x8 v1 = *reinterpret_cast<const bf16x8*>(
                Vb + vrow + (((2 + h2) ^ sw) << 4));
            yacc[ct] = mfma32(pa0, v0, yacc[ct]);
            yacc[ct] = mfma32(pa1, v1, yacc[ct]);
        }

        asm volatile("" ::: "memory");
        __builtin_amdgcn_s_barrier();
        __builtin_amdgcn_sched_barrier(0);
        const int tmp = ia; ia = ib; ib = ic; ic = tmp;
    }

    const float ylt = ylrun + __shfl_xor(ylrun, 32);
    const int bc = chunk * 4 + b;
    #pragma unroll
    for (int ct = 0; ct < 4; ++ct)
        #pragma unroll
        for (int r = 0; r < 16; ++r) {
            const int q = Q0 + (r & 3) + 8 * (r >> 2) + 4 * h2;
            yPart[((size_t)bc * 4096 + q) * 128 + ct * 32 + l31] = (__bf16)yacc[ct][r];
        }
    if (h2 == 0)
        lPart[(size_t)bc * 4096 + Q0 + l31] = ylt;
}

// ---------------- Merge the NC KV-chunk partials: yT = sum(y_c)/sum(l_c), bf16 --------------
template<int NC>
__global__ __launch_bounds__(256) void merge_kernel(
    const __bf16* __restrict__ yPart, const float* __restrict__ lPart,
    __bf16* __restrict__ yT)
{
    const int idx = blockIdx.x * 256 + threadIdx.x;  // 524288 total
    const int row = idx >> 5;
    const int c4  = (idx & 31) * 4;
    float lsum = 0.f;
    #pragma unroll
    for (int c = 0; c < NC; ++c) lsum += lPart[(size_t)c * 16384 + row];
    const float inv = 1.0f / lsum;
    float s[4] = {0.f, 0.f, 0.f, 0.f};
    #pragma unroll
    for (int c = 0; c < NC; ++c) {
        bf16x4 v = *reinterpret_cast<const bf16x4*>(
            yPart + (size_t)c * 2097152 + (size_t)row * 128 + c4);
        #pragma unroll
        for (int i = 0; i < 4; ++i) s[i] += (float)v[i];
    }
    bf16x4 o;
    #pragma unroll
    for (int i = 0; i < 4; ++i) o[i] = (__bf16)(s[i] * inv);
    *reinterpret_cast<bf16x4*>(yT + (size_t)row * 128 + c4) = o;
}

// ---------------- wy MFMA + fused BN partial stats ------------------------------------------
// Wy[b,o,n] = sum_ci W[o,ci] yT[b,n,ci] + Wb[o]; per-block per-o partial sum/sumsq written
// deterministically (no atomics) to pSQ[ [128][256] sums | [128][256] sumsqs ].
__global__ __launch_bounds__(256, 1) void wy_mfma(
    const __bf16* __restrict__ yT, const __bf16* __restrict__ wW,
    const float* __restrict__ Wb, float* __restrict__ Wy, float* __restrict__ pSQ)
{
    const int b    = blockIdx.y;
    const int n0   = blockIdx.x * 128;
    const int w    = threadIdx.x >> 6;
    const int lane = threadIdx.x & 63;
    const int lo   = lane & 15;
    const int hi   = lane >> 4;

    __shared__ alignas(16) __bf16 YL[128 * 128];
    __shared__ alignas(16) __bf16 WL[256 * 128];

    const __bf16* ybase = yT + ((size_t)b * 4096 + n0) * 128;
    #pragma unroll
    for (int u = 0; u < 8; ++u) {
        const int chunk = (w * 8 + u) * 64 + lane;
        const int row   = chunk >> 4;
        const int jb    = (chunk & 15) * 16;
        const int sb    = row * 256 + (jb ^ ((row & 7) << 4));
        GLOAD_LDS16(ybase + (sb >> 1), &YL[(w * 8 + u) * 512]);
    }
    #pragma unroll
    for (int u = 0; u < 16; ++u) {
        const int chunk = (w * 16 + u) * 64 + lane;
        const int row   = chunk >> 4;
        const int jb    = (chunk & 15) * 16;
        const int sb    = row * 256 + (jb ^ ((row & 7) << 4));
        GLOAD_LDS16(wW + (sb >> 1), &WL[(w * 16 + u) * 512]);
    }
    __syncthreads();

    f32x4 C[4][8];
    #pragma unroll
    for (int og = 0; og < 4; ++og)
        #pragma unroll
        for (int ct = 0; ct < 8; ++ct) C[og][ct] = f32x4{0.f, 0.f, 0.f, 0.f};

    #pragma unroll
    for (int kb = 0; kb < 4; ++kb) {
        const int koff = kb * 64 + hi * 16;
        bf16x8 a[4], bb[8];
        #pragma unroll
        for (int og = 0; og < 4; ++og) {
            const int o = w * 64 + og * 16 + lo;
            a[og] = *reinterpret_cast<const bf16x8*>(
                (const char*)WL + o * 256 + (koff ^ ((o & 7) << 4)));
        }
        #pragma unroll
        for (int ct = 0; ct < 8; ++ct) {
            const int nl = ct * 16 + lo;
            bb[ct] = *reinterpret_cast<const bf16x8*>(
                (const char*)YL + nl * 256 + (koff ^ ((nl & 7) << 4)));
        }
        #pragma unroll
        for (int og = 0; og < 4; ++og)
            #pragma unroll
            for (int ct = 0; ct < 8; ++ct)
                C[og][ct] = mfma16(a[og], bb[ct], C[og][ct]);
    }

    const int blk = blockIdx.y * 32 + blockIdx.x;   // 0..127
    #pragma unroll
    for (int og = 0; og < 4; ++og)
        #pragma unroll
        for (int r = 0; r < 4; ++r) {
            const int o  = w * 64 + og * 16 + 4 * hi + r;
            const float bv = Wb[o];
            float s = 0.f, q = 0.f;
            #pragma unroll
            for (int ct = 0; ct < 8; ++ct) {
                const float v = C[og][ct][r] + bv;
                Wy[((size_t)b * 256 + o) * 4096 + n0 + ct * 16 + lo] = v;
                s += v; q += v * v;
            }
            #pragma unroll
            for (int off = 1; off <= 8; off <<= 1) {
                s += __shfl_xor(s, off);
                q += __shfl_xor(q, off);
            }
            if (lo == 0) {
                pSQ[blk * 256 + o]         = s;
                pSQ[32768 + blk * 256 + o] = q;
            }
        }
}

// ---------------- stats finalize: reduce 128 partials per channel ---------------------------
__global__ __launch_bounds__(128) void stats_finalize(
    const float* __restrict__ pSQ, const float* __restrict__ gamma,
    const float* __restrict__ beta, float* __restrict__ stats)
{
    const int o = blockIdx.x;       // 256 blocks
    const int t = threadIdx.x;      // 128 threads = 128 partials
    float s = pSQ[t * 256 + o];
    float q = pSQ[32768 + t * 256 + o];
    #pragma unroll
    for (int off = 32; off >= 1; off >>= 1) {
        s += __shfl_down(s, off);
        q += __shfl_down(q, off);
    }
    __shared__ float red[4];
    if ((t & 63) == 0) { red[t >> 6] = s; red[2 + (t >> 6)] = q; }
    __syncthreads();
    if (t == 0) {
        const float S = red[0] + red[1];
        const float Q = red[2] + red[3];
        const float mean = S * (1.f / 16384.f);
        const float var  = Q * (1.f / 16384.f) - mean * mean;
        const float scl  = gamma[o] * rsqrtf(var + 1e-5f);
        stats[o]       = scl;
        stats[256 + o] = beta[o] - mean * scl;
    }
}

// ---------------- out = Wy*scale + shift + x ------------------------------------------------
__global__ __launch_bounds__(256) void final_kernel(
    const float* __restrict__ Wy, const float* __restrict__ x,
    const float* __restrict__ stats, float* __restrict__ out)
{
    const int idx = blockIdx.x * 256 + threadIdx.x;
    const int o   = (idx >> 10) & 255;
    f32x4 wy = *reinterpret_cast<const f32x4*>(Wy + (size_t)idx * 4);
    f32x4 xv = *reinterpret_cast<const f32x4*>(x  + (size_t)idx * 4);
    f32x4 res = wy * stats[o] + stats[256 + o] + xv;
    *reinterpret_cast<f32x4*>(out + (size_t)idx * 4) = res;
}

extern "C" void kernel_launch(void* const* d_in, const int* in_sizes, int n_in,
                              void* d_out, int out_size, void* d_ws, size_t ws_size,
                              hipStream_t stream)
{
    const float* x    = (const float*)d_in[0];
    const float* g_w  = (const float*)d_in[1];
    const float* g_b  = (const float*)d_in[2];
    const float* th_w = (const float*)d_in[3];
    const float* th_b = (const float*)d_in[4];
    const float* ph_w = (const float*)d_in[5];
    const float* ph_b = (const float*)d_in[6];
    const float* W_w  = (const float*)d_in[7];
    const float* W_b  = (const float*)d_in[8];
    const float* bn_g = (const float*)d_in[9];
    const float* bn_b = (const float*)d_in[10];
    float* out = (float*)d_out;

    // Workspace: thetaT@0, phiT@4M, gBlk@8M, gT@12M, xT@16M(8M).
    // yPart@12M (over dead gT/xT): 32MB (8-chunk) or 16MB (4-chunk).
    // After attn: yT@0, Wy@4M..20M, pSQ@20M (256KB, over dead yPart tail).
    char* ws = (char*)d_ws;
    const size_t MB = 1u << 20;
    __bf16* thetaT = (__bf16*)(ws);
    __bf16* phiT   = (__bf16*)(ws + 4 * MB);
    __bf16* gBlk   = (__bf16*)(ws + 8 * MB);
    __bf16* gT     = (__bf16*)(ws + 12 * MB);
    __bf16* xT     = (__bf16*)(ws + 16 * MB);
    __bf16* yPart  = (__bf16*)(ws + 12 * MB);
    __bf16* yT     = (__bf16*)(ws);
    float*  Wy     = (float*) (ws + 4 * MB);
    float*  pSQ    = (float*) (ws + 20 * MB);

    const bool big = ws_size >= 46926848ull;
    const size_t tail = big ? 44 * MB : 28 * MB;
    float*  lPart = (float*) (ws + tail);
    __bf16* wbf   = (__bf16*)(ws + tail + (big ? 524288 : 262144));
    float*  stats = (float*) (ws + tail + (big ? 786432 : 524288));

    prep_w<<<dim3(128), 256, 0, stream>>>(th_w, ph_w, g_w, W_w, wbf);
    xT_kernel<<<dim3(64, 4, 4), 256, 0, stream>>>(x, xT);
    proj_mfma<<<dim3(64, 3, 4), 256, 0, stream>>>(
        xT, wbf, th_b, ph_b, g_b, thetaT, phiT, gT);
    transpose_g<<<dim3(64, 2, 4), 256, 0, stream>>>(gT, gBlk);
    if (big) {
        attn_kernel<8><<<dim3(1024), 256, 0, stream>>>(thetaT, phiT, gBlk, yPart, lPart);
        merge_kernel<8><<<dim3(2048), 256, 0, stream>>>(yPart, lPart, yT);
    } else {
        attn_kernel<4><<<dim3(512), 256, 0, stream>>>(thetaT, phiT, gBlk, yPart, lPart);
        merge_kernel<4><<<dim3(2048), 256, 0, stream>>>(yPart, lPart, yT);
    }
    wy_mfma<<<dim3(32, 4), 256, 0, stream>>>(yT, wbf + 98304, W_b, Wy, pSQ);
    stats_finalize<<<dim3(256), 128, 0, stream>>>(pSQ, bn_g, bn_b, stats);
    final_kernel<<<dim3(4096), 256, 0, stream>>>(Wy, x, stats, out);
}